// Round 4
// baseline (971.341 us; speedup 1.0000x reference)
//
#include <hip/hip_runtime.h>

// ---------------------------------------------------------------------------
// CONTEXTUAL_AUTOENCODER: B=2048, IN=9016 (att 312 | desc 512 | gpt 16x512)
//   q = desc@Wq+bq; kstats from gpt@Wk+bk epilogue; softmax -> attn_mean;
//   g~ = sum_v am[v]*gpt -> fused = g~@Wv+bv; z,h,out MLP.
// R1: 1-D grid + bijective XCD swizzle + panel-reuse fast-dim decode.
// R3: 256x256 8-phase GEMM (T2 swizzle + counted vmcnt + setprio).
// R4: split-K round-packing: out ks=4 (1152 blk, 90% packed, fp32 atomics),
//     h ks=2 (256 blk, 100% packed, atomics->f32 scratch + relu-cast).
// ---------------------------------------------------------------------------

typedef __bf16 bf16x8 __attribute__((ext_vector_type(8)));
typedef float  f32x4  __attribute__((ext_vector_type(4)));
typedef unsigned short u16;

#define ATT   312
#define WEMB  512
#define VIEW  16
#define ADIM  2048
#define EMB   2048
#define BATCH 2048
#define INDIM 9016
#define KCAT  2360
#define KCATP 2432
#define NOUT  9016
#define NOUTP 9216   // 36 x 256 tiles

__device__ __forceinline__ u16 f2bf(float f) {
  unsigned u = __builtin_bit_cast(unsigned, f);
  u += 0x7FFFu + ((u >> 16) & 1u);            // RNE
  return (u16)(u >> 16);
}

__device__ __forceinline__ void gl_lds16(const u16* g, u16* l) {
  __builtin_amdgcn_global_load_lds((const __attribute__((address_space(1))) void*)g,
                                   (__attribute__((address_space(3))) void*)l, 16, 0, 0);
}

// --- cast x into concat-att cols, desc A-matrix, gpt A-matrix (bf16) --------
__global__ void castx_k(const float* __restrict__ x, u16* __restrict__ cc,
                        u16* __restrict__ desc, u16* __restrict__ gpt) {
  const int b = blockIdx.x, t = threadIdx.x;
  const float4* row = (const float4*)(x + (size_t)b * INDIM);
  for (int c = t; c < INDIM / 4; c += 256) {
    float4 v = row[c];
    ushort4 o = make_ushort4(f2bf(v.x), f2bf(v.y), f2bf(v.z), f2bf(v.w));
    if (c < ATT / 4)                 *(ushort4*)&cc[(size_t)b * KCATP + c * 4] = o;
    else if (c < (ATT + WEMB) / 4)   *(ushort4*)&desc[(size_t)b * WEMB + (c - ATT / 4) * 4] = o;
    else                             *(ushort4*)&gpt[(size_t)b * (VIEW * WEMB) + (c - (ATT + WEMB) / 4) * 4] = o;
  }
}

// --- transpose-cast: src[K][N] fp32 -> dst[Np][Kp] bf16 (zero padded) -------
__global__ void transcast_k(const float* __restrict__ src, u16* __restrict__ dst,
                            int K, int N, int Kp, int Np) {
  __shared__ float tile[64][65];
  const int k0 = blockIdx.y * 64, n0 = blockIdx.x * 64;
  const int t = threadIdx.x;
  const int tr = t >> 4, tc4 = (t & 15) * 4;
#pragma unroll
  for (int i = 0; i < 4; ++i) {
    const int k = k0 + tr + i * 16;
    float v0 = 0.f, v1 = 0.f, v2 = 0.f, v3 = 0.f;
    if (k < K) {
      const int n = n0 + tc4;
      const float* p = src + (size_t)k * N + n;
      if (n + 3 < N) { float4 v = *(const float4*)p; v0 = v.x; v1 = v.y; v2 = v.z; v3 = v.w; }
      else {
        if (n + 0 < N) v0 = p[0];
        if (n + 1 < N) v1 = p[1];
        if (n + 2 < N) v2 = p[2];
        if (n + 3 < N) v3 = p[3];
      }
    }
    tile[tr + i * 16][tc4 + 0] = v0;
    tile[tr + i * 16][tc4 + 1] = v1;
    tile[tr + i * 16][tc4 + 2] = v2;
    tile[tr + i * 16][tc4 + 3] = v3;
  }
  __syncthreads();
#pragma unroll
  for (int i = 0; i < 4; ++i) {
    const int rn = tr + i * 16;
    const int n = n0 + rn;
    const int kk = k0 + tc4;
    if (n < Np) {
      const bool nv = (n < N);
      ushort4 o = make_ushort4(f2bf(nv ? tile[tc4 + 0][rn] : 0.f),
                               f2bf(nv ? tile[tc4 + 1][rn] : 0.f),
                               f2bf(nv ? tile[tc4 + 2][rn] : 0.f),
                               f2bf(nv ? tile[tc4 + 3][rn] : 0.f));
      *(ushort4*)&dst[(size_t)n * Kp + kk] = o;
    }
  }
}

// ===========================================================================
// 256x256 8-phase GEMM with K-split. A[M][K] bf16, BT[N][K] bf16.
// 8 waves (2M x 4N), per-wave 128x64 out. LDS 128KB, st_16x32-class swizzle.
// Grid = mt*nt*ks, kslice fastest. Phase ledger as R3 (verified).
// MODE 2: kstats epilogue. MODE 3: atomicAdd fp32 (+bias on slice 0).
// ===========================================================================
__device__ __forceinline__ void stage_half(const u16* __restrict__ src, int ld,
                                           u16* dst, int wave, int lane) {
#pragma unroll
  for (int j = 0; j < 2; ++j) {
    const int s = wave * 2 + j;                    // subtile 0..15
    const int r = ((s >> 1) << 4) + (lane >> 2);   // logical row in half
    const int c = ((s & 1) << 5) +
                  (((lane & 3) << 3) ^ (((lane >> 5) & 1) << 4));  // inv-swz col
    gl_lds16(src + (long)r * ld + c, dst + s * 512 + (lane << 3));
  }
}

#define BAR   __builtin_amdgcn_s_barrier()
#define LGKM0 asm volatile("s_waitcnt lgkmcnt(0)" ::: "memory")
#define VM6   asm volatile("s_waitcnt vmcnt(6)" ::: "memory")
#define VM0   asm volatile("s_waitcnt vmcnt(0)" ::: "memory")

#define RDA(bufo) do { _Pragma("unroll") for (int mf = 0; mf < 8; ++mf) \
  _Pragma("unroll") for (int kk = 0; kk < 2; ++kk) \
    a[mf][kk] = *(const bf16x8*)&lds[(bufo) + aoff0 + (mf * 2 + kk) * 512]; } while (0)
#define RDB(bufo, nfa, nfb) do { _Pragma("unroll") for (int nf = (nfa); nf <= (nfb); ++nf) \
  _Pragma("unroll") for (int kk = 0; kk < 2; ++kk) \
    b[nf][kk] = *(const bf16x8*)&lds[(bufo) + boff0 + nf * 1024 + kk * 512]; } while (0)
#define QUAD(qm, qn) do { __builtin_amdgcn_s_setprio(1); \
  _Pragma("unroll") for (int m4 = 0; m4 < 4; ++m4) \
  _Pragma("unroll") for (int n2 = 0; n2 < 2; ++n2) \
  _Pragma("unroll") for (int kk = 0; kk < 2; ++kk) \
    acc[(qm) * 4 + m4][(qn) * 2 + n2] = __builtin_amdgcn_mfma_f32_16x16x32_bf16( \
        a[(qm) * 4 + m4][kk], b[(qn) * 2 + n2][kk], acc[(qm) * 4 + m4][(qn) * 2 + n2], 0, 0, 0); \
  __builtin_amdgcn_s_setprio(0); } while (0)

template <int MODE>
__global__ __launch_bounds__(512, 2)
void gemm256(const u16* __restrict__ A, const u16* __restrict__ BT,
             const float* __restrict__ bias, int K, int Nreal,
             float* __restrict__ dstF, int ldc,
             const float* __restrict__ qbuf, float* __restrict__ dotb,
             float* __restrict__ kn2b, int mt, int nt, int fastm,
             int ks, int kl) {
  __shared__ alignas(16) u16 lds[65536];   // 128 KB
  const int nwg = mt * nt * ks;
  const int xcd = blockIdx.x & 7, idx = blockIdx.x >> 3;
  const int qq = nwg >> 3, rr = nwg & 7;
  const int wg = (xcd < rr ? xcd * (qq + 1) : rr * (qq + 1) + (xcd - rr) * qq) + idx;
  const int ksl = wg % ks;
  const int rem = wg / ks;
  int tm, tn;
  if (fastm) { tm = rem % mt; tn = rem / mt; } else { tn = rem % nt; tm = rem / nt; }

  const int tid = threadIdx.x;
  const int wave = tid >> 6, lane = tid & 63;
  const long m0 = (long)tm * 256, n0 = (long)tn * 256;
  const int wm = wave >> 2, wn = wave & 3;          // 2 x 4 wave grid
  const u16* Ab = A + m0 * K + (long)ksl * kl;
  const u16* Bb = BT + n0 * K + (long)ksl * kl;

  f32x4 acc[8][4] = {};
  bf16x8 a[8][2], b[4][2];
  const int LP = (lane & 15) * 32 + ((((lane >> 4) << 3)) ^ (((lane >> 3) & 1) << 4));
  const int aoff0 = wm * 8192 + LP;
  const int boff0 = 16384 + (wn >> 1) * 8192 + (wn & 1) * 4096 + LP;
  const int NT = kl >> 6;

  // prologue: tile0 (4 halves) + tile1 {A0,A1,B0}; vmcnt(6) => tile0 landed
  stage_half(Ab,                K, &lds[0],     wave, lane);
  stage_half(Ab + 128 * K,      K, &lds[8192],  wave, lane);
  stage_half(Bb,                K, &lds[16384], wave, lane);
  stage_half(Bb + 128 * K,      K, &lds[24576], wave, lane);
  stage_half(Ab + 64,           K, &lds[32768], wave, lane);
  stage_half(Ab + 128 * K + 64, K, &lds[40960], wave, lane);
  stage_half(Bb + 64,           K, &lds[49152], wave, lane);
  VM6; BAR;

  const int iters = NT >> 1;
  for (int i = 0; i < iters; ++i) {
    const int t0 = 2 * i;
    const bool nl = (i < iters - 1);
    // P1
    RDA(0); RDB(0, 0, 1);
    stage_half(Bb + 128 * K + (t0 + 1) * 64, K, &lds[57344], wave, lane);
    BAR; LGKM0; QUAD(0, 0); BAR;
    // P2
    RDB(0, 2, 3);
    if (nl) stage_half(Ab + (t0 + 2) * 64, K, &lds[0], wave, lane);
    BAR; LGKM0; QUAD(1, 0); BAR;
    // P3
    if (nl) stage_half(Ab + 128 * K + (t0 + 2) * 64, K, &lds[8192], wave, lane);
    BAR; QUAD(0, 1); BAR;
    // P4
    if (nl) stage_half(Bb + (t0 + 2) * 64, K, &lds[16384], wave, lane);
    BAR; QUAD(1, 1);
    if (nl) { VM6; } else { VM0; }
    BAR;
    // P5
    RDA(32768); RDB(32768, 0, 1);
    if (nl) stage_half(Bb + 128 * K + (t0 + 2) * 64, K, &lds[24576], wave, lane);
    BAR; LGKM0; QUAD(0, 0); BAR;
    // P6
    RDB(32768, 2, 3);
    if (nl) stage_half(Ab + (t0 + 3) * 64, K, &lds[32768], wave, lane);
    BAR; LGKM0; QUAD(1, 0); BAR;
    // P7
    if (nl) stage_half(Ab + 128 * K + (t0 + 3) * 64, K, &lds[40960], wave, lane);
    BAR; QUAD(0, 1); BAR;
    // P8
    if (nl) stage_half(Bb + (t0 + 3) * 64, K, &lds[49152], wave, lane);
    BAR; QUAD(1, 1);
    if (nl) VM6;
    BAR;
  }

  const int lr = lane >> 4, lc = lane & 15;
  if (MODE == 2) {
#pragma unroll
    for (int mf = 0; mf < 8; ++mf) {
#pragma unroll
      for (int r = 0; r < 4; ++r) {
        const long grow = m0 + wm * 128 + mf * 16 + lr * 4 + r;
        const long bb = grow >> 4;
        float ds = 0.f, ks2 = 0.f;
#pragma unroll
        for (int nf = 0; nf < 4; ++nf) {
          const long col = n0 + wn * 64 + nf * 16 + lc;
          float kv = acc[mf][nf][r] + bias[col];
          ds += kv * qbuf[bb * ADIM + col];
          ks2 += kv * kv;
        }
#pragma unroll
        for (int m = 1; m < 16; m <<= 1) {
          ds += __shfl_xor(ds, m, 64);
          ks2 += __shfl_xor(ks2, m, 64);
        }
        if (lc == 0) {
          atomicAdd(&dotb[grow], ds);
          atomicAdd(&kn2b[grow], ks2);
        }
      }
    }
  } else {  // MODE 3: fp32 atomic accumulate, bias on slice 0
#pragma unroll
    for (int mf = 0; mf < 8; ++mf) {
#pragma unroll
      for (int nf = 0; nf < 4; ++nf) {
        const long col = n0 + wn * 64 + nf * 16 + lc;
        if (col < Nreal) {
          const float bv_ = (ksl == 0) ? bias[col] : 0.f;
#pragma unroll
          for (int r = 0; r < 4; ++r) {
            const long row = m0 + wm * 128 + mf * 16 + lr * 4 + r;
            atomicAdd(&dstF[row * (long)ldc + col], acc[mf][nf][r] + bv_);
          }
        }
      }
    }
  }
}

// --- relu + cast fp32 -> bf16 -----------------------------------------------
__global__ void relucast_k(const float* __restrict__ src, u16* __restrict__ dst) {
  const int i = (blockIdx.x * 256 + threadIdx.x) * 8;
  float4 va = *(const float4*)&src[i];
  float4 vb = *(const float4*)&src[i + 4];
  ushort4 o0 = make_ushort4(f2bf(fmaxf(va.x, 0.f)), f2bf(fmaxf(va.y, 0.f)),
                            f2bf(fmaxf(va.z, 0.f)), f2bf(fmaxf(va.w, 0.f)));
  ushort4 o1 = make_ushort4(f2bf(fmaxf(vb.x, 0.f)), f2bf(fmaxf(vb.y, 0.f)),
                            f2bf(fmaxf(vb.z, 0.f)), f2bf(fmaxf(vb.w, 0.f)));
  *(ushort4*)&dst[i] = o0;
  *(ushort4*)&dst[i + 4] = o1;
}

// --- 128x128 2-phase GEMM (kept for z / q / fused) --------------------------
template <int MODE, bool RELU>
__global__ __launch_bounds__(256, 2)
void gemm_bt(const u16* __restrict__ A, const u16* __restrict__ BT,
             const float* __restrict__ bias, int K, int Nreal,
             float* __restrict__ dstF, u16* __restrict__ dstH, int ldc,
             int mt, int nt, int fastm) {
  __shared__ alignas(16) u16 Ash[128 * 64];
  __shared__ alignas(16) u16 Bsh[128 * 64];
  const int nwg = mt * nt;
  const int xcd = blockIdx.x & 7, idx = blockIdx.x >> 3;
  const int qq = nwg >> 3, rr = nwg & 7;
  const int wg = (xcd < rr ? xcd * (qq + 1) : rr * (qq + 1) + (xcd - rr) * qq) + idx;
  int tm, tn;
  if (fastm) { tm = wg % mt; tn = wg / mt; } else { tn = wg % nt; tm = wg / nt; }

  const int tid = threadIdx.x;
  const int wave = tid >> 6, lane = tid & 63;
  const long m0 = (long)tm * 128;
  const long n0 = (long)tn * 128;
  const int wm = wave >> 1, wnn = wave & 1;
  f32x4 acc[4][4] = {};

  const int srow = (wave << 5) + (lane >> 3);
  const int scol = (lane & 7) << 3;

  for (int k0 = 0; k0 < K; k0 += 64) {
    __syncthreads();
#pragma unroll
    for (int i = 0; i < 4; ++i) {
      const int r = srow + i * 8;
      gl_lds16(A + (m0 + r) * (long)K + k0 + scol, &Ash[r * 64 + scol]);
      gl_lds16(BT + (n0 + r) * (long)K + k0 + scol, &Bsh[r * 64 + scol]);
    }
    __syncthreads();
#pragma unroll
    for (int kb = 0; kb < 2; ++kb) {
      bf16x8 af[4], bfv[4];
#pragma unroll
      for (int f = 0; f < 4; ++f) {
        af[f]  = *(const bf16x8*)&Ash[(wm * 64 + f * 16 + (lane & 15)) * 64 + kb * 32 + (lane >> 4) * 8];
        bfv[f] = *(const bf16x8*)&Bsh[(wnn * 64 + f * 16 + (lane & 15)) * 64 + kb * 32 + (lane >> 4) * 8];
      }
#pragma unroll
      for (int mf = 0; mf < 4; ++mf)
#pragma unroll
        for (int nf = 0; nf < 4; ++nf)
          acc[mf][nf] = __builtin_amdgcn_mfma_f32_16x16x32_bf16(af[mf], bfv[nf], acc[mf][nf], 0, 0, 0);
    }
  }

  const int lr = lane >> 4, lc = lane & 15;
#pragma unroll
  for (int mf = 0; mf < 4; ++mf) {
#pragma unroll
    for (int nf = 0; nf < 4; ++nf) {
      const long col = n0 + wnn * 64 + nf * 16 + lc;
      if (col < Nreal) {
        const float bv_ = bias[col];
#pragma unroll
        for (int r = 0; r < 4; ++r) {
          const long row = m0 + wm * 64 + mf * 16 + lr * 4 + r;
          float v = acc[mf][nf][r] + bv_;
          if (RELU) v = fmaxf(v, 0.f);
          if (MODE == 0) dstF[row * (long)ldc + col] = v;
          else           dstH[row * (long)ldc + col] = f2bf(v);
        }
      }
    }
  }
}

// --- qn2[b] = |q[b,:]|^2 ----------------------------------------------------
__global__ void qnorm_k(const float* __restrict__ q, float* __restrict__ qn2) {
  const int b = blockIdx.x, t = threadIdx.x;
  const float4* row = (const float4*)(q + (size_t)b * ADIM);
  float s = 0.f;
#pragma unroll
  for (int i = 0; i < 2; ++i) {
    float4 v = row[t + i * 256];
    s += v.x * v.x + v.y * v.y + v.z * v.z + v.w * v.w;
  }
#pragma unroll
  for (int m = 1; m < 64; m <<= 1) s += __shfl_xor(s, m, 64);
  __shared__ float wsum[4];
  if ((t & 63) == 0) wsum[t >> 6] = s;
  __syncthreads();
  if (t == 0) qn2[b] = wsum[0] + wsum[1] + wsum[2] + wsum[3];
}

// --- per-row softmax of cs*ed, accumulate attn sums -------------------------
__global__ void attn_k(const float* __restrict__ dotb, const float* __restrict__ kn2b,
                       const float* __restrict__ qn2, float* __restrict__ asum) {
  const int b = blockIdx.x * 256 + threadIdx.x;
  const int lane = threadIdx.x & 63;
  const float q2 = qn2[b];
  const float qn = fmaxf(sqrtf(q2), 1e-8f);
  float lg[VIEW];
  float mx = -1e30f;
#pragma unroll
  for (int v = 0; v < VIEW; ++v) {
    const float d = dotb[b * VIEW + v], k2 = kn2b[b * VIEW + v];
    const float kn = fmaxf(sqrtf(k2), 1e-8f);
    const float cs = d / (qn * kn);
    const float ed = sqrtf(fmaxf(q2 - 2.f * d + k2, 0.f));
    lg[v] = cs * ed;
    mx = fmaxf(mx, lg[v]);
  }
  float s = 0.f;
#pragma unroll
  for (int v = 0; v < VIEW; ++v) { lg[v] = expf(lg[v] - mx); s += lg[v]; }
  const float inv = 1.f / s;
#pragma unroll
  for (int v = 0; v < VIEW; ++v) {
    float aa = lg[v] * inv;
#pragma unroll
    for (int m = 1; m < 64; m <<= 1) aa += __shfl_xor(aa, m, 64);
    if (lane == 0) atomicAdd(&asum[v], aa);
  }
}

// --- g~[b,w] = sum_v attn_mean[v]*gpt[b,v,w] (bf16 in, bf16 out) ------------
__global__ void gtilde_k(const u16* __restrict__ gpt, const float* __restrict__ asum,
                         u16* __restrict__ g) {
  const int b = blockIdx.x, t = threadIdx.x;  // 64 threads, 8 cols each
  float am[VIEW];
#pragma unroll
  for (int v = 0; v < VIEW; ++v) am[v] = asum[v] * (1.f / (float)BATCH);
  float s[8] = {};
  const u16* gx = gpt + (size_t)b * (VIEW * WEMB) + t * 8;
#pragma unroll
  for (int v = 0; v < VIEW; ++v) {
    bf16x8 gv = *(const bf16x8*)&gx[v * WEMB];
#pragma unroll
    for (int j = 0; j < 8; ++j) s[j] += am[v] * (float)gv[j];
  }
  ushort4 o0, o1;
  o0 = make_ushort4(f2bf(s[0]), f2bf(s[1]), f2bf(s[2]), f2bf(s[3]));
  o1 = make_ushort4(f2bf(s[4]), f2bf(s[5]), f2bf(s[6]), f2bf(s[7]));
  *(ushort4*)&g[(size_t)b * WEMB + t * 8] = o0;
  *(ushort4*)&g[(size_t)b * WEMB + t * 8 + 4] = o1;
}

// ---------------------------------------------------------------------------
extern "C" void kernel_launch(void* const* d_in, const int* in_sizes, int n_in,
                              void* d_out, int out_size, void* d_ws, size_t ws_size,
                              hipStream_t stream) {
  const float* x   = (const float*)d_in[0];
  const float* Wq  = (const float*)d_in[1];
  const float* bq  = (const float*)d_in[2];
  const float* Wk  = (const float*)d_in[3];
  const float* bk  = (const float*)d_in[4];
  const float* Wv  = (const float*)d_in[5];
  const float* bv  = (const float*)d_in[6];
  const float* Wm  = (const float*)d_in[7];
  const float* bm  = (const float*)d_in[8];
  const float* Wd1 = (const float*)d_in[9];
  const float* bd1 = (const float*)d_in[10];
  const float* Wd2 = (const float*)d_in[11];
  const float* bd2 = (const float*)d_in[12];
  float* out = (float*)d_out;

  char* ws = (char*)d_ws;
  size_t off = 0;
  auto alloc = [&](size_t bytes) -> void* {
    void* p = ws + off;
    off = (off + bytes + 255) & ~(size_t)255;
    return p;
  };
  u16* WqT  = (u16*)alloc((size_t)ADIM * WEMB * 2);
  u16* WkT  = (u16*)alloc((size_t)ADIM * WEMB * 2);
  u16* WvT  = (u16*)alloc((size_t)ADIM * WEMB * 2);
  u16* WmT  = (u16*)alloc((size_t)EMB * KCATP * 2);
  u16* Wd1T = (u16*)alloc((size_t)4096 * EMB * 2);
  u16* Wd2T = (u16*)alloc((size_t)NOUTP * 4096 * 2);
  u16* desc = (u16*)alloc((size_t)BATCH * WEMB * 2);
  u16* gpt  = (u16*)alloc((size_t)BATCH * VIEW * WEMB * 2);
  u16* cc   = (u16*)alloc((size_t)BATCH * KCATP * 2);
  float* q    = (float*)alloc((size_t)BATCH * ADIM * 4);
  float* qn2  = (float*)alloc((size_t)BATCH * 4);
  float* stats = (float*)alloc((size_t)(BATCH * VIEW * 2 + 64) * 4);
  float* dotb = stats;
  float* kn2b = stats + BATCH * VIEW;
  float* asum = stats + BATCH * VIEW * 2;
  u16* gt = (u16*)alloc((size_t)BATCH * WEMB * 2);
  u16* z  = (u16*)alloc((size_t)BATCH * EMB * 2);
  u16* h  = (u16*)alloc((size_t)BATCH * 4096 * 2);
  if (off > ws_size) return;  // workspace too small -> clean validation fail
  // h32 (fp32 split-K accumulator for h) aliases desc+gpt (dead by then):
  // 2048*4096*4 = 32 MiB <= desc(2 MiB)+gpt(32 MiB).
  float* h32 = (float*)desc;

  hipMemsetAsync(out, 0, (size_t)out_size * 4, stream);   // split-K target
  hipMemsetAsync(stats, 0, (size_t)(BATCH * VIEW * 2 + 64) * 4, stream);
  hipMemsetAsync(cc, 0, (size_t)BATCH * KCATP * 2, stream);

  castx_k<<<BATCH, 256, 0, stream>>>(x, cc, desc, gpt);

  transcast_k<<<dim3(ADIM / 64, WEMB / 64), 256, 0, stream>>>(Wq, WqT, WEMB, ADIM, WEMB, ADIM);
  transcast_k<<<dim3(ADIM / 64, WEMB / 64), 256, 0, stream>>>(Wk, WkT, WEMB, ADIM, WEMB, ADIM);
  transcast_k<<<dim3(ADIM / 64, WEMB / 64), 256, 0, stream>>>(Wv, WvT, WEMB, ADIM, WEMB, ADIM);
  transcast_k<<<dim3(EMB / 64, KCATP / 64), 256, 0, stream>>>(Wm, WmT, KCAT, EMB, KCATP, EMB);
  transcast_k<<<dim3(4096 / 64, EMB / 64), 256, 0, stream>>>(Wd1, Wd1T, EMB, 4096, EMB, 4096);
  transcast_k<<<dim3(NOUTP / 64, 4096 / 64), 256, 0, stream>>>(Wd2, Wd2T, 4096, NOUT, 4096, NOUTP);

  // q = desc @ Wq + bq (fp32 out), 128^2, grid 256, N-fast
  gemm_bt<0, false><<<16 * 16, 256, 0, stream>>>(
      desc, WqT, bq, WEMB, ADIM, q, nullptr, ADIM, BATCH / 128, ADIM / 128, 0);
  qnorm_k<<<BATCH, 256, 0, stream>>>(q, qn2);
  // kstats: 256^2 8-phase, grid 1024 (= exactly 4 rounds), N-fast
  gemm256<2><<<128 * 8, 512, 0, stream>>>(
      gpt, WkT, bk, WEMB, ADIM, nullptr, 0, q, dotb, kn2b,
      BATCH * VIEW / 256, ADIM / 256, 0, 1, WEMB);
  attn_k<<<BATCH / 256, 256, 0, stream>>>(dotb, kn2b, qn2, asum);
  gtilde_k<<<BATCH, 64, 0, stream>>>(gpt, asum, gt);
  // fused = g~ @ Wv + bv -> concat cols [312, 2360), 128^2
  gemm_bt<1, false><<<16 * 16, 256, 0, stream>>>(
      gt, WvT, bv, WEMB, ADIM, nullptr, cc + ATT, KCATP, BATCH / 128, ADIM / 128, 0);
  // z = relu(concat @ Wm + bm), 128^2 grid 256
  gemm_bt<1, true><<<16 * 16, 256, 0, stream>>>(
      cc, WmT, bm, KCATP, EMB, nullptr, z, EMB, BATCH / 128, EMB / 128, 0);
  // ---- h = relu(z @ Wd1 + bd1): split-K=2 -> 256 blocks (exactly 1 round)
  hipMemsetAsync(h32, 0, (size_t)BATCH * 4096 * 4, stream);  // kills desc/gpt
  gemm256<3><<<8 * 16 * 2, 512, 0, stream>>>(
      z, Wd1T, bd1, EMB, 4096, h32, 4096, nullptr, nullptr, nullptr,
      BATCH / 256, 4096 / 256, 1, 2, EMB / 2);
  relucast_k<<<(BATCH * 4096) / 2048, 256, 0, stream>>>(h32, h);
  // ---- out = h @ Wd2 + bd2: split-K=4 -> 1152 blocks (~90% packed), M-fast
  gemm256<3><<<8 * 36 * 4, 512, 0, stream>>>(
      h, Wd2T, bd2, 4096, NOUT, out, NOUT, nullptr, nullptr, nullptr,
      BATCH / 256, NOUTP / 256, 1, 4, 1024);
}

// Round 5
// 708.104 us; speedup vs baseline: 1.3717x; 1.3717x over previous
//
#include <hip/hip_runtime.h>

// ---------------------------------------------------------------------------
// CONTEXTUAL_AUTOENCODER: B=2048, IN=9016 (att 312 | desc 512 | gpt 16x512)
//   q = desc@Wq+bq; kstats from gpt@Wk+bk epilogue; softmax -> attn_mean;
//   g~ = sum_v am[v]*gpt -> fused = g~@Wv+bv; z,h,out MLP.
// R1: 1-D grid + bijective XCD swizzle + panel-reuse fast-dim decode.
// R3: 256x256 8-phase GEMM (T2 swizzle + counted vmcnt + setprio).
// R4: FAILED (split-K fp32 atomics: 288 MB RMW epilogue) -> reverted.
// R5: balanced-read ledger: reads 12/8/4/0 per phase; stages A0@P3,A1@P4,
//     B0@P5,B1@P6,A0'@P7,{A1',B0'}@P8,B1'@P1; vmcnt(4)@P4, vmcnt(6)@P8.
// ---------------------------------------------------------------------------

typedef __bf16 bf16x8 __attribute__((ext_vector_type(8)));
typedef float  f32x4  __attribute__((ext_vector_type(4)));
typedef unsigned short u16;

#define ATT   312
#define WEMB  512
#define VIEW  16
#define ADIM  2048
#define EMB   2048
#define BATCH 2048
#define INDIM 9016
#define KCAT  2360
#define KCATP 2432
#define NOUT  9016
#define NOUTP 9216   // 36 x 256 tiles

__device__ __forceinline__ u16 f2bf(float f) {
  unsigned u = __builtin_bit_cast(unsigned, f);
  u += 0x7FFFu + ((u >> 16) & 1u);            // RNE
  return (u16)(u >> 16);
}

__device__ __forceinline__ void gl_lds16(const u16* g, u16* l) {
  __builtin_amdgcn_global_load_lds((const __attribute__((address_space(1))) void*)g,
                                   (__attribute__((address_space(3))) void*)l, 16, 0, 0);
}

// --- cast x into concat-att cols, desc A-matrix, gpt A-matrix (bf16) --------
__global__ void castx_k(const float* __restrict__ x, u16* __restrict__ cc,
                        u16* __restrict__ desc, u16* __restrict__ gpt) {
  const int b = blockIdx.x, t = threadIdx.x;
  const float4* row = (const float4*)(x + (size_t)b * INDIM);
  for (int c = t; c < INDIM / 4; c += 256) {
    float4 v = row[c];
    ushort4 o = make_ushort4(f2bf(v.x), f2bf(v.y), f2bf(v.z), f2bf(v.w));
    if (c < ATT / 4)                 *(ushort4*)&cc[(size_t)b * KCATP + c * 4] = o;
    else if (c < (ATT + WEMB) / 4)   *(ushort4*)&desc[(size_t)b * WEMB + (c - ATT / 4) * 4] = o;
    else                             *(ushort4*)&gpt[(size_t)b * (VIEW * WEMB) + (c - (ATT + WEMB) / 4) * 4] = o;
  }
}

// --- transpose-cast: src[K][N] fp32 -> dst[Np][Kp] bf16 (zero padded) -------
__global__ void transcast_k(const float* __restrict__ src, u16* __restrict__ dst,
                            int K, int N, int Kp, int Np) {
  __shared__ float tile[64][65];
  const int k0 = blockIdx.y * 64, n0 = blockIdx.x * 64;
  const int t = threadIdx.x;
  const int tr = t >> 4, tc4 = (t & 15) * 4;
#pragma unroll
  for (int i = 0; i < 4; ++i) {
    const int k = k0 + tr + i * 16;
    float v0 = 0.f, v1 = 0.f, v2 = 0.f, v3 = 0.f;
    if (k < K) {
      const int n = n0 + tc4;
      const float* p = src + (size_t)k * N + n;
      if (n + 3 < N) { float4 v = *(const float4*)p; v0 = v.x; v1 = v.y; v2 = v.z; v3 = v.w; }
      else {
        if (n + 0 < N) v0 = p[0];
        if (n + 1 < N) v1 = p[1];
        if (n + 2 < N) v2 = p[2];
        if (n + 3 < N) v3 = p[3];
      }
    }
    tile[tr + i * 16][tc4 + 0] = v0;
    tile[tr + i * 16][tc4 + 1] = v1;
    tile[tr + i * 16][tc4 + 2] = v2;
    tile[tr + i * 16][tc4 + 3] = v3;
  }
  __syncthreads();
#pragma unroll
  for (int i = 0; i < 4; ++i) {
    const int rn = tr + i * 16;
    const int n = n0 + rn;
    const int kk = k0 + tc4;
    if (n < Np) {
      const bool nv = (n < N);
      ushort4 o = make_ushort4(f2bf(nv ? tile[tc4 + 0][rn] : 0.f),
                               f2bf(nv ? tile[tc4 + 1][rn] : 0.f),
                               f2bf(nv ? tile[tc4 + 2][rn] : 0.f),
                               f2bf(nv ? tile[tc4 + 3][rn] : 0.f));
      *(ushort4*)&dst[(size_t)n * Kp + kk] = o;
    }
  }
}

// ===========================================================================
// 256x256 8-phase GEMM. A[M][K] bf16, BT[N][K] bf16. 8 waves (2M x 4N),
// per-wave 128x64 out. LDS 128KB: buf{0,1} x {A0,A1,B0,B1} halves (16KB ea),
// subtiled [16][32] with st_16x32 XOR swizzle.
// R5 ledger (iter i: buf0=tile 2i [P1-4], buf1=tile 2i+1 [P5-8]):
//   reads : P1 a0-3,b0-1 | P2 a4-7 | P3 b2-3 | P4 - (same P5-P7 on buf1)
//   stages: B1b1(2i+1)@P1, A0b0(2i+2)@P3, A1b0@P4, B0b0@P5, B1b0@P6,
//           A0b1(2i+3)@P7, {A1b1,B0b1}@P8
//   FIFO-verified: vmcnt(4)@P4 => tile 2i+1 landed; vmcnt(6)@P8 => 2i+2 landed.
// ===========================================================================
__device__ __forceinline__ void stage_half(const u16* __restrict__ src, int ld,
                                           u16* dst, int wave, int lane) {
#pragma unroll
  for (int j = 0; j < 2; ++j) {
    const int s = wave * 2 + j;                    // subtile 0..15
    const int r = ((s >> 1) << 4) + (lane >> 2);   // logical row in half
    const int c = ((s & 1) << 5) +
                  (((lane & 3) << 3) ^ (((lane >> 5) & 1) << 4));  // inv-swz col
    gl_lds16(src + (long)r * ld + c, dst + s * 512 + (lane << 3));
  }
}

#define BAR   __builtin_amdgcn_s_barrier()
#define LGKM0 asm volatile("s_waitcnt lgkmcnt(0)" ::: "memory")
#define VM6   asm volatile("s_waitcnt vmcnt(6)" ::: "memory")
#define VM4   asm volatile("s_waitcnt vmcnt(4)" ::: "memory")
#define VM0   asm volatile("s_waitcnt vmcnt(0)" ::: "memory")

#define RDA(bufo, lo, hi) do { _Pragma("unroll") for (int mf = (lo); mf <= (hi); ++mf) \
  _Pragma("unroll") for (int kk = 0; kk < 2; ++kk) \
    a[mf][kk] = *(const bf16x8*)&lds[(bufo) + aoff0 + (mf * 2 + kk) * 512]; } while (0)
#define RDB(bufo, lo, hi) do { _Pragma("unroll") for (int nf = (lo); nf <= (hi); ++nf) \
  _Pragma("unroll") for (int kk = 0; kk < 2; ++kk) \
    b[nf][kk] = *(const bf16x8*)&lds[(bufo) + boff0 + nf * 1024 + kk * 512]; } while (0)
#define QUAD(qm, qn) do { __builtin_amdgcn_s_setprio(1); \
  _Pragma("unroll") for (int m4 = 0; m4 < 4; ++m4) \
  _Pragma("unroll") for (int n2 = 0; n2 < 2; ++n2) \
  _Pragma("unroll") for (int kk = 0; kk < 2; ++kk) \
    acc[(qm) * 4 + m4][(qn) * 2 + n2] = __builtin_amdgcn_mfma_f32_16x16x32_bf16( \
        a[(qm) * 4 + m4][kk], b[(qn) * 2 + n2][kk], acc[(qm) * 4 + m4][(qn) * 2 + n2], 0, 0, 0); \
  __builtin_amdgcn_s_setprio(0); } while (0)

template <int MODE, bool RELU>
__global__ __launch_bounds__(512, 2)
void gemm256(const u16* __restrict__ A, const u16* __restrict__ BT,
             const float* __restrict__ bias, int K, int Nreal,
             float* __restrict__ dstF, u16* __restrict__ dstH, int ldc,
             const float* __restrict__ qbuf, float* __restrict__ dotb,
             float* __restrict__ kn2b, int mt, int nt, int fastm) {
  __shared__ alignas(16) u16 lds[65536];   // 128 KB
  const int nwg = mt * nt;
  const int xcd = blockIdx.x & 7, idx = blockIdx.x >> 3;
  const int qq = nwg >> 3, rr = nwg & 7;
  const int wg = (xcd < rr ? xcd * (qq + 1) : rr * (qq + 1) + (xcd - rr) * qq) + idx;
  int tm, tn;
  if (fastm) { tm = wg % mt; tn = wg / mt; } else { tn = wg % nt; tm = wg / nt; }

  const int tid = threadIdx.x;
  const int wave = tid >> 6, lane = tid & 63;
  const long m0 = (long)tm * 256, n0 = (long)tn * 256;
  const int wm = wave >> 2, wn = wave & 3;          // 2 x 4 wave grid
  const u16* Ab = A + m0 * K;
  const u16* Bb = BT + n0 * K;

  f32x4 acc[8][4] = {};
  bf16x8 a[8][2], b[4][2];
  const int LP = (lane & 15) * 32 + ((((lane >> 4) << 3)) ^ (((lane >> 3) & 1) << 4));
  const int aoff0 = wm * 8192 + LP;
  const int boff0 = 16384 + (wn >> 1) * 8192 + (wn & 1) * 4096 + LP;
  const int NT = K >> 6;

  // prologue: buf0 tile0 (4 halves) + buf1 tile1 {A0,A1,B0}; vmcnt(6) =>
  // buf0 landed, 6 outstanding = steady state.
  stage_half(Ab,                K, &lds[0],     wave, lane);
  stage_half(Ab + 128 * K,      K, &lds[8192],  wave, lane);
  stage_half(Bb,                K, &lds[16384], wave, lane);
  stage_half(Bb + 128 * K,      K, &lds[24576], wave, lane);
  stage_half(Ab + 64,           K, &lds[32768], wave, lane);
  stage_half(Ab + 128 * K + 64, K, &lds[40960], wave, lane);
  stage_half(Bb + 64,           K, &lds[49152], wave, lane);
  VM6; BAR;

  const int iters = NT >> 1;
  for (int i = 0; i < iters; ++i) {
    const int t0 = 2 * i;
    const bool nl = (i < iters - 1);
    // P1: reads a0-3,b0-1 (12); stage B1buf1(2i+1)
    RDA(0, 0, 3); RDB(0, 0, 1);
    stage_half(Bb + 128 * K + (t0 + 1) * 64, K, &lds[57344], wave, lane);
    BAR; LGKM0; QUAD(0, 0); BAR;
    // P2: reads a4-7 (8)
    RDA(0, 4, 7);
    BAR; LGKM0; QUAD(1, 0); BAR;
    // P3: reads b2-3 (4); stage A0buf0(2i+2)
    RDB(0, 2, 3);
    if (nl) stage_half(Ab + (t0 + 2) * 64, K, &lds[0], wave, lane);
    BAR; LGKM0; QUAD(0, 1); BAR;
    // P4: stage A1buf0(2i+2); vmcnt(4) => tile 2i+1 landed
    if (nl) stage_half(Ab + 128 * K + (t0 + 2) * 64, K, &lds[8192], wave, lane);
    BAR; QUAD(1, 1);
    if (nl) { VM4; } else { VM0; }
    BAR;
    // P5: reads buf1 a0-3,b0-1 (12); stage B0buf0(2i+2)
    RDA(32768, 0, 3); RDB(32768, 0, 1);
    if (nl) stage_half(Bb + (t0 + 2) * 64, K, &lds[16384], wave, lane);
    BAR; LGKM0; QUAD(0, 0); BAR;
    // P6: reads buf1 a4-7 (8); stage B1buf0(2i+2)
    RDA(32768, 4, 7);
    if (nl) stage_half(Bb + 128 * K + (t0 + 2) * 64, K, &lds[24576], wave, lane);
    BAR; LGKM0; QUAD(1, 0); BAR;
    // P7: reads buf1 b2-3 (4); stage A0buf1(2i+3)
    RDB(32768, 2, 3);
    if (nl) stage_half(Ab + (t0 + 3) * 64, K, &lds[32768], wave, lane);
    BAR; LGKM0; QUAD(0, 1); BAR;
    // P8: stage A1buf1(2i+3) + B0buf1(2i+3); vmcnt(6) => tile 2i+2 landed
    if (nl) {
      stage_half(Ab + 128 * K + (t0 + 3) * 64, K, &lds[40960], wave, lane);
      stage_half(Bb + (t0 + 3) * 64, K, &lds[49152], wave, lane);
    }
    BAR; QUAD(1, 1);
    if (nl) VM6;
    BAR;
  }

  const int lr = lane >> 4, lc = lane & 15;
  if (MODE == 2) {
#pragma unroll
    for (int mf = 0; mf < 8; ++mf) {
#pragma unroll
      for (int r = 0; r < 4; ++r) {
        const long grow = m0 + wm * 128 + mf * 16 + lr * 4 + r;
        const long bb = grow >> 4;
        float ds = 0.f, ks2 = 0.f;
#pragma unroll
        for (int nf = 0; nf < 4; ++nf) {
          const long col = n0 + wn * 64 + nf * 16 + lc;
          float kv = acc[mf][nf][r] + bias[col];
          ds += kv * qbuf[bb * ADIM + col];
          ks2 += kv * kv;
        }
#pragma unroll
        for (int m = 1; m < 16; m <<= 1) {
          ds += __shfl_xor(ds, m, 64);
          ks2 += __shfl_xor(ks2, m, 64);
        }
        if (lc == 0) {
          atomicAdd(&dotb[grow], ds);
          atomicAdd(&kn2b[grow], ks2);
        }
      }
    }
  } else {
#pragma unroll
    for (int mf = 0; mf < 8; ++mf) {
#pragma unroll
      for (int nf = 0; nf < 4; ++nf) {
        const long col = n0 + wn * 64 + nf * 16 + lc;
        if (col < Nreal) {
          const float bv_ = bias[col];
#pragma unroll
          for (int r = 0; r < 4; ++r) {
            const long row = m0 + wm * 128 + mf * 16 + lr * 4 + r;
            float v = acc[mf][nf][r] + bv_;
            if (RELU) v = fmaxf(v, 0.f);
            if (MODE == 0) dstF[row * (long)ldc + col] = v;
            else           dstH[row * (long)ldc + col] = f2bf(v);
          }
        }
      }
    }
  }
}

// --- 128x128 2-phase GEMM (kept for z / q / fused) --------------------------
template <int MODE, bool RELU>
__global__ __launch_bounds__(256, 2)
void gemm_bt(const u16* __restrict__ A, const u16* __restrict__ BT,
             const float* __restrict__ bias, int K, int Nreal,
             float* __restrict__ dstF, u16* __restrict__ dstH, int ldc,
             int mt, int nt, int fastm) {
  __shared__ alignas(16) u16 Ash[128 * 64];
  __shared__ alignas(16) u16 Bsh[128 * 64];
  const int nwg = mt * nt;
  const int xcd = blockIdx.x & 7, idx = blockIdx.x >> 3;
  const int qq = nwg >> 3, rr = nwg & 7;
  const int wg = (xcd < rr ? xcd * (qq + 1) : rr * (qq + 1) + (xcd - rr) * qq) + idx;
  int tm, tn;
  if (fastm) { tm = wg % mt; tn = wg / mt; } else { tn = wg % nt; tm = wg / nt; }

  const int tid = threadIdx.x;
  const int wave = tid >> 6, lane = tid & 63;
  const long m0 = (long)tm * 128;
  const long n0 = (long)tn * 128;
  const int wm = wave >> 1, wnn = wave & 1;
  f32x4 acc[4][4] = {};

  const int srow = (wave << 5) + (lane >> 3);
  const int scol = (lane & 7) << 3;

  for (int k0 = 0; k0 < K; k0 += 64) {
    __syncthreads();
#pragma unroll
    for (int i = 0; i < 4; ++i) {
      const int r = srow + i * 8;
      gl_lds16(A + (m0 + r) * (long)K + k0 + scol, &Ash[r * 64 + scol]);
      gl_lds16(BT + (n0 + r) * (long)K + k0 + scol, &Bsh[r * 64 + scol]);
    }
    __syncthreads();
#pragma unroll
    for (int kb = 0; kb < 2; ++kb) {
      bf16x8 af[4], bfv[4];
#pragma unroll
      for (int f = 0; f < 4; ++f) {
        af[f]  = *(const bf16x8*)&Ash[(wm * 64 + f * 16 + (lane & 15)) * 64 + kb * 32 + (lane >> 4) * 8];
        bfv[f] = *(const bf16x8*)&Bsh[(wnn * 64 + f * 16 + (lane & 15)) * 64 + kb * 32 + (lane >> 4) * 8];
      }
#pragma unroll
      for (int mf = 0; mf < 4; ++mf)
#pragma unroll
        for (int nf = 0; nf < 4; ++nf)
          acc[mf][nf] = __builtin_amdgcn_mfma_f32_16x16x32_bf16(af[mf], bfv[nf], acc[mf][nf], 0, 0, 0);
    }
  }

  const int lr = lane >> 4, lc = lane & 15;
#pragma unroll
  for (int mf = 0; mf < 4; ++mf) {
#pragma unroll
    for (int nf = 0; nf < 4; ++nf) {
      const long col = n0 + wnn * 64 + nf * 16 + lc;
      if (col < Nreal) {
        const float bv_ = bias[col];
#pragma unroll
        for (int r = 0; r < 4; ++r) {
          const long row = m0 + wm * 64 + mf * 16 + lr * 4 + r;
          float v = acc[mf][nf][r] + bv_;
          if (RELU) v = fmaxf(v, 0.f);
          if (MODE == 0) dstF[row * (long)ldc + col] = v;
          else           dstH[row * (long)ldc + col] = f2bf(v);
        }
      }
    }
  }
}

// --- qn2[b] = |q[b,:]|^2 ----------------------------------------------------
__global__ void qnorm_k(const float* __restrict__ q, float* __restrict__ qn2) {
  const int b = blockIdx.x, t = threadIdx.x;
  const float4* row = (const float4*)(q + (size_t)b * ADIM);
  float s = 0.f;
#pragma unroll
  for (int i = 0; i < 2; ++i) {
    float4 v = row[t + i * 256];
    s += v.x * v.x + v.y * v.y + v.z * v.z + v.w * v.w;
  }
#pragma unroll
  for (int m = 1; m < 64; m <<= 1) s += __shfl_xor(s, m, 64);
  __shared__ float wsum[4];
  if ((t & 63) == 0) wsum[t >> 6] = s;
  __syncthreads();
  if (t == 0) qn2[b] = wsum[0] + wsum[1] + wsum[2] + wsum[3];
}

// --- per-row softmax of cs*ed, accumulate attn sums -------------------------
__global__ void attn_k(const float* __restrict__ dotb, const float* __restrict__ kn2b,
                       const float* __restrict__ qn2, float* __restrict__ asum) {
  const int b = blockIdx.x * 256 + threadIdx.x;
  const int lane = threadIdx.x & 63;
  const float q2 = qn2[b];
  const float qn = fmaxf(sqrtf(q2), 1e-8f);
  float lg[VIEW];
  float mx = -1e30f;
#pragma unroll
  for (int v = 0; v < VIEW; ++v) {
    const float d = dotb[b * VIEW + v], k2 = kn2b[b * VIEW + v];
    const float kn = fmaxf(sqrtf(k2), 1e-8f);
    const float cs = d / (qn * kn);
    const float ed = sqrtf(fmaxf(q2 - 2.f * d + k2, 0.f));
    lg[v] = cs * ed;
    mx = fmaxf(mx, lg[v]);
  }
  float s = 0.f;
#pragma unroll
  for (int v = 0; v < VIEW; ++v) { lg[v] = expf(lg[v] - mx); s += lg[v]; }
  const float inv = 1.f / s;
#pragma unroll
  for (int v = 0; v < VIEW; ++v) {
    float aa = lg[v] * inv;
#pragma unroll
    for (int m = 1; m < 64; m <<= 1) aa += __shfl_xor(aa, m, 64);
    if (lane == 0) atomicAdd(&asum[v], aa);
  }
}

// --- g~[b,w] = sum_v attn_mean[v]*gpt[b,v,w] (bf16 in, bf16 out) ------------
__global__ void gtilde_k(const u16* __restrict__ gpt, const float* __restrict__ asum,
                         u16* __restrict__ g) {
  const int b = blockIdx.x, t = threadIdx.x;  // 64 threads, 8 cols each
  float am[VIEW];
#pragma unroll
  for (int v = 0; v < VIEW; ++v) am[v] = asum[v] * (1.f / (float)BATCH);
  float s[8] = {};
  const u16* gx = gpt + (size_t)b * (VIEW * WEMB) + t * 8;
#pragma unroll
  for (int v = 0; v < VIEW; ++v) {
    bf16x8 gv = *(const bf16x8*)&gx[v * WEMB];
#pragma unroll
    for (int j = 0; j < 8; ++j) s[j] += am[v] * (float)gv[j];
  }
  ushort4 o0, o1;
  o0 = make_ushort4(f2bf(s[0]), f2bf(s[1]), f2bf(s[2]), f2bf(s[3]));
  o1 = make_ushort4(f2bf(s[4]), f2bf(s[5]), f2bf(s[6]), f2bf(s[7]));
  *(ushort4*)&g[(size_t)b * WEMB + t * 8] = o0;
  *(ushort4*)&g[(size_t)b * WEMB + t * 8 + 4] = o1;
}

// ---------------------------------------------------------------------------
extern "C" void kernel_launch(void* const* d_in, const int* in_sizes, int n_in,
                              void* d_out, int out_size, void* d_ws, size_t ws_size,
                              hipStream_t stream) {
  const float* x   = (const float*)d_in[0];
  const float* Wq  = (const float*)d_in[1];
  const float* bq  = (const float*)d_in[2];
  const float* Wk  = (const float*)d_in[3];
  const float* bk  = (const float*)d_in[4];
  const float* Wv  = (const float*)d_in[5];
  const float* bv  = (const float*)d_in[6];
  const float* Wm  = (const float*)d_in[7];
  const float* bm  = (const float*)d_in[8];
  const float* Wd1 = (const float*)d_in[9];
  const float* bd1 = (const float*)d_in[10];
  const float* Wd2 = (const float*)d_in[11];
  const float* bd2 = (const float*)d_in[12];
  float* out = (float*)d_out;

  char* ws = (char*)d_ws;
  size_t off = 0;
  auto alloc = [&](size_t bytes) -> void* {
    void* p = ws + off;
    off = (off + bytes + 255) & ~(size_t)255;
    return p;
  };
  u16* WqT  = (u16*)alloc((size_t)ADIM * WEMB * 2);
  u16* WkT  = (u16*)alloc((size_t)ADIM * WEMB * 2);
  u16* WvT  = (u16*)alloc((size_t)ADIM * WEMB * 2);
  u16* WmT  = (u16*)alloc((size_t)EMB * KCATP * 2);
  u16* Wd1T = (u16*)alloc((size_t)4096 * EMB * 2);
  u16* Wd2T = (u16*)alloc((size_t)NOUTP * 4096 * 2);
  u16* desc = (u16*)alloc((size_t)BATCH * WEMB * 2);
  u16* gpt  = (u16*)alloc((size_t)BATCH * VIEW * WEMB * 2);
  u16* cc   = (u16*)alloc((size_t)BATCH * KCATP * 2);
  float* q    = (float*)alloc((size_t)BATCH * ADIM * 4);
  float* qn2  = (float*)alloc((size_t)BATCH * 4);
  float* stats = (float*)alloc((size_t)(BATCH * VIEW * 2 + 64) * 4);
  float* dotb = stats;
  float* kn2b = stats + BATCH * VIEW;
  float* asum = stats + BATCH * VIEW * 2;
  u16* gt = (u16*)alloc((size_t)BATCH * WEMB * 2);
  u16* z  = (u16*)alloc((size_t)BATCH * EMB * 2);
  u16* h  = (u16*)alloc((size_t)BATCH * 4096 * 2);
  if (off > ws_size) return;  // workspace too small -> clean validation fail

  hipMemsetAsync(stats, 0, (size_t)(BATCH * VIEW * 2 + 64) * 4, stream);
  hipMemsetAsync(cc, 0, (size_t)BATCH * KCATP * 2, stream);

  castx_k<<<BATCH, 256, 0, stream>>>(x, cc, desc, gpt);

  transcast_k<<<dim3(ADIM / 64, WEMB / 64), 256, 0, stream>>>(Wq, WqT, WEMB, ADIM, WEMB, ADIM);
  transcast_k<<<dim3(ADIM / 64, WEMB / 64), 256, 0, stream>>>(Wk, WkT, WEMB, ADIM, WEMB, ADIM);
  transcast_k<<<dim3(ADIM / 64, WEMB / 64), 256, 0, stream>>>(Wv, WvT, WEMB, ADIM, WEMB, ADIM);
  transcast_k<<<dim3(EMB / 64, KCATP / 64), 256, 0, stream>>>(Wm, WmT, KCAT, EMB, KCATP, EMB);
  transcast_k<<<dim3(4096 / 64, EMB / 64), 256, 0, stream>>>(Wd1, Wd1T, EMB, 4096, EMB, 4096);
  transcast_k<<<dim3(NOUTP / 64, 4096 / 64), 256, 0, stream>>>(Wd2, Wd2T, 4096, NOUT, 4096, NOUTP);

  // q = desc @ Wq + bq (fp32 out), 128^2, grid 256, N-fast
  gemm_bt<0, false><<<16 * 16, 256, 0, stream>>>(
      desc, WqT, bq, WEMB, ADIM, q, nullptr, ADIM, BATCH / 128, ADIM / 128, 0);
  qnorm_k<<<BATCH, 256, 0, stream>>>(q, qn2);
  // kstats: 256^2 8-phase, grid 1024 (= exactly 4 rounds), N-fast
  gemm256<2, false><<<128 * 8, 512, 0, stream>>>(
      gpt, WkT, bk, WEMB, ADIM, nullptr, nullptr, 0, q, dotb, kn2b,
      BATCH * VIEW / 256, ADIM / 256, 0);
  attn_k<<<BATCH / 256, 256, 0, stream>>>(dotb, kn2b, qn2, asum);
  gtilde_k<<<BATCH, 64, 0, stream>>>(gpt, asum, gt);
  // fused = g~ @ Wv + bv -> concat cols [312, 2360), 128^2
  gemm_bt<1, false><<<16 * 16, 256, 0, stream>>>(
      gt, WvT, bv, WEMB, ADIM, nullptr, cc + ATT, KCATP, BATCH / 128, ADIM / 128, 0);
  // z = relu(concat @ Wm + bm), 128^2 grid 256
  gemm_bt<1, true><<<16 * 16, 256, 0, stream>>>(
      cc, WmT, bm, KCATP, EMB, nullptr, z, EMB, BATCH / 128, EMB / 128, 0);
  // h = relu(z @ Wd1 + bd1), 256^2 8-phase, grid 128, M-fast (share B panel)
  gemm256<1, true><<<8 * 16, 512, 0, stream>>>(
      z, Wd1T, bd1, EMB, 4096, nullptr, h, 4096, nullptr, nullptr, nullptr,
      BATCH / 256, 4096 / 256, 1);
  // out = h @ Wd2 + bd2 (fp32, guarded at 9016), 256^2 8-phase, grid 288, M-fast
  gemm256<0, false><<<8 * 36, 512, 0, stream>>>(
      h, Wd2T, bd2, 4096, NOUT, out, nullptr, NOUT, nullptr, nullptr, nullptr,
      BATCH / 256, NOUTP / 256, 1);
}

// Round 7
// 690.420 us; speedup vs baseline: 1.4069x; 1.0256x over previous
//
#include <hip/hip_runtime.h>

// ---------------------------------------------------------------------------
// CONTEXTUAL_AUTOENCODER: B=2048, IN=9016 (att 312 | desc 512 | gpt 16x512)
//   q = desc@Wq+bq; kstats from gpt@Wk+bk epilogue; softmax -> attn_mean;
//   g~ = sum_v am[v]*gpt -> fused = g~@Wv+bv; z,h,out MLP.
// R1: 1-D grid + bijective XCD swizzle + panel-reuse fast-dim decode.
// R3: 256x256 8-phase GEMM (T2 swizzle + counted vmcnt + setprio).
// R4: FAILED (split-K fp32 atomics: 288 MB RMW epilogue) -> reverted.
// R5: balanced-read ledger (null -> in-round limiter is L3 supply, not lgkm).
// R6: FAILED: Pout (70.44 MB) overran arena desc..z (69.76 MB) by 712,448 B
//     into h -> NaN. R7: +1 MB pad in arena; transcast6 tiles Kp not K.
// ---------------------------------------------------------------------------

typedef __bf16 bf16x8 __attribute__((ext_vector_type(8)));
typedef float  f32x4  __attribute__((ext_vector_type(4)));
typedef unsigned short u16;

#define ATT   312
#define WEMB  512
#define VIEW  16
#define ADIM  2048
#define EMB   2048
#define BATCH 2048
#define INDIM 9016
#define KCAT  2360
#define KCATP 2432
#define NOUT  9016
#define NOUTP 9216   // 36 x 256 tiles

__device__ __forceinline__ u16 f2bf(float f) {
  unsigned u = __builtin_bit_cast(unsigned, f);
  u += 0x7FFFu + ((u >> 16) & 1u);            // RNE
  return (u16)(u >> 16);
}

__device__ __forceinline__ void gl_lds16(const u16* g, u16* l) {
  __builtin_amdgcn_global_load_lds((const __attribute__((address_space(1))) void*)g,
                                   (__attribute__((address_space(3))) void*)l, 16, 0, 0);
}

// --- cast x into concat-att cols (+zero pad), desc, gpt (bf16) --------------
__global__ void castx_k(const float* __restrict__ x, u16* __restrict__ cc,
                        u16* __restrict__ desc, u16* __restrict__ gpt) {
  const int b = blockIdx.x, t = threadIdx.x;
  const float4* row = (const float4*)(x + (size_t)b * INDIM);
  for (int c = t; c < INDIM / 4; c += 256) {
    float4 v = row[c];
    ushort4 o = make_ushort4(f2bf(v.x), f2bf(v.y), f2bf(v.z), f2bf(v.w));
    if (c < ATT / 4)                 *(ushort4*)&cc[(size_t)b * KCATP + c * 4] = o;
    else if (c < (ATT + WEMB) / 4)   *(ushort4*)&desc[(size_t)b * WEMB + (c - ATT / 4) * 4] = o;
    else                             *(ushort4*)&gpt[(size_t)b * (VIEW * WEMB) + (c - (ATT + WEMB) / 4) * 4] = o;
  }
  // zero-fill K-pad cols [KCAT, KCATP) of cc (replaces memset)
  if (t < (KCATP - KCAT) / 4) {
    *(ushort4*)&cc[(size_t)b * KCATP + KCAT + t * 4] = make_ushort4(0, 0, 0, 0);
  }
}

// --- fused transpose-cast of all 6 weights: src[K][N] f32 -> dst[Np][Kp] ----
struct TcDesc { const float* src; u16* dst; int K, N, Kp, Np, ntx, base; };
struct TcArgs { TcDesc d[6]; };

__global__ void transcast6_k(TcArgs A) {
  __shared__ float tile[64][65];
  int mi = 0;
  const int bid = blockIdx.x;
#pragma unroll
  for (int i = 1; i < 6; ++i) if (bid >= A.d[i].base) mi = i;
  const TcDesc& D = A.d[mi];
  const int local = bid - D.base;
  const int n0 = (local % D.ntx) * 64, k0 = (local / D.ntx) * 64;
  const int t = threadIdx.x;
  const int tr = t >> 4, tc4 = (t & 15) * 4;
#pragma unroll
  for (int i = 0; i < 4; ++i) {
    const int k = k0 + tr + i * 16;
    float v0 = 0.f, v1 = 0.f, v2 = 0.f, v3 = 0.f;
    if (k < D.K) {
      const int n = n0 + tc4;
      const float* p = D.src + (size_t)k * D.N + n;
      if (n + 3 < D.N) { float4 v = *(const float4*)p; v0 = v.x; v1 = v.y; v2 = v.z; v3 = v.w; }
      else {
        if (n + 0 < D.N) v0 = p[0];
        if (n + 1 < D.N) v1 = p[1];
        if (n + 2 < D.N) v2 = p[2];
        if (n + 3 < D.N) v3 = p[3];
      }
    }
    tile[tr + i * 16][tc4 + 0] = v0;
    tile[tr + i * 16][tc4 + 1] = v1;
    tile[tr + i * 16][tc4 + 2] = v2;
    tile[tr + i * 16][tc4 + 3] = v3;
  }
  __syncthreads();
#pragma unroll
  for (int i = 0; i < 4; ++i) {
    const int rn = tr + i * 16;
    const int n = n0 + rn;
    const int kk = k0 + tc4;
    if (n < D.Np && kk < D.Kp) {
      const bool nv = (n < D.N);
      ushort4 o = make_ushort4(f2bf(nv ? tile[tc4 + 0][rn] : 0.f),
                               f2bf(nv ? tile[tc4 + 1][rn] : 0.f),
                               f2bf(nv ? tile[tc4 + 2][rn] : 0.f),
                               f2bf(nv ? tile[tc4 + 3][rn] : 0.f));
      *(ushort4*)&D.dst[(size_t)n * D.Kp + kk] = o;
    }
  }
}

// ===========================================================================
// 256x256 8-phase GEMM (R5 balanced ledger, verified) with optional K-split.
// MODE 1: bf16 store (+RELU). MODE 2: kstats epilogue.
// MODE 4: split-K pair — ksl 0: fp32 direct store + bias; ksl 1: fp32 partial.
// ===========================================================================
__device__ __forceinline__ void stage_half(const u16* __restrict__ src, int ld,
                                           u16* dst, int wave, int lane) {
#pragma unroll
  for (int j = 0; j < 2; ++j) {
    const int s = wave * 2 + j;                    // subtile 0..15
    const int r = ((s >> 1) << 4) + (lane >> 2);   // logical row in half
    const int c = ((s & 1) << 5) +
                  (((lane & 3) << 3) ^ (((lane >> 5) & 1) << 4));  // inv-swz col
    gl_lds16(src + (long)r * ld + c, dst + s * 512 + (lane << 3));
  }
}

#define BAR   __builtin_amdgcn_s_barrier()
#define LGKM0 asm volatile("s_waitcnt lgkmcnt(0)" ::: "memory")
#define VM6   asm volatile("s_waitcnt vmcnt(6)" ::: "memory")
#define VM4   asm volatile("s_waitcnt vmcnt(4)" ::: "memory")
#define VM0   asm volatile("s_waitcnt vmcnt(0)" ::: "memory")

#define RDA(bufo, lo, hi) do { _Pragma("unroll") for (int mf = (lo); mf <= (hi); ++mf) \
  _Pragma("unroll") for (int kk = 0; kk < 2; ++kk) \
    a[mf][kk] = *(const bf16x8*)&lds[(bufo) + aoff0 + (mf * 2 + kk) * 512]; } while (0)
#define RDB(bufo, lo, hi) do { _Pragma("unroll") for (int nf = (lo); nf <= (hi); ++nf) \
  _Pragma("unroll") for (int kk = 0; kk < 2; ++kk) \
    b[nf][kk] = *(const bf16x8*)&lds[(bufo) + boff0 + nf * 1024 + kk * 512]; } while (0)
#define QUAD(qm, qn) do { __builtin_amdgcn_s_setprio(1); \
  _Pragma("unroll") for (int m4 = 0; m4 < 4; ++m4) \
  _Pragma("unroll") for (int n2 = 0; n2 < 2; ++n2) \
  _Pragma("unroll") for (int kk = 0; kk < 2; ++kk) \
    acc[(qm) * 4 + m4][(qn) * 2 + n2] = __builtin_amdgcn_mfma_f32_16x16x32_bf16( \
        a[(qm) * 4 + m4][kk], b[(qn) * 2 + n2][kk], acc[(qm) * 4 + m4][(qn) * 2 + n2], 0, 0, 0); \
  __builtin_amdgcn_s_setprio(0); } while (0)

template <int MODE, bool RELU>
__global__ __launch_bounds__(512, 2)
void gemm256(const u16* __restrict__ A, const u16* __restrict__ BT,
             const float* __restrict__ bias, int K, int Nreal,
             float* __restrict__ dstF, u16* __restrict__ dstH,
             float* __restrict__ PF, int ldc,
             const float* __restrict__ qbuf, float* __restrict__ dotb,
             float* __restrict__ kn2b, int mt, int nt, int fastm,
             int ks, int kl) {
  __shared__ alignas(16) u16 lds[65536];   // 128 KB
  const int nwg = mt * nt * ks;
  const int xcd = blockIdx.x & 7, idx = blockIdx.x >> 3;
  const int qq = nwg >> 3, rr = nwg & 7;
  const int wg = (xcd < rr ? xcd * (qq + 1) : rr * (qq + 1) + (xcd - rr) * qq) + idx;
  const int ksl = wg % ks;
  const int rem = wg / ks;
  int tm, tn;
  if (fastm) { tm = rem % mt; tn = rem / mt; } else { tn = rem % nt; tm = rem / nt; }

  const int tid = threadIdx.x;
  const int wave = tid >> 6, lane = tid & 63;
  const long m0 = (long)tm * 256, n0 = (long)tn * 256;
  const int wm = wave >> 2, wn = wave & 3;          // 2 x 4 wave grid
  const u16* Ab = A + m0 * K + (long)ksl * kl;
  const u16* Bb = BT + n0 * K + (long)ksl * kl;

  f32x4 acc[8][4] = {};
  bf16x8 a[8][2], b[4][2];
  const int LP = (lane & 15) * 32 + ((((lane >> 4) << 3)) ^ (((lane >> 3) & 1) << 4));
  const int aoff0 = wm * 8192 + LP;
  const int boff0 = 16384 + (wn >> 1) * 8192 + (wn & 1) * 4096 + LP;
  const int NT = kl >> 6;

  // prologue: buf0 tile0 (4 halves) + buf1 tile1 {A0,A1,B0}
  stage_half(Ab,                K, &lds[0],     wave, lane);
  stage_half(Ab + 128 * K,      K, &lds[8192],  wave, lane);
  stage_half(Bb,                K, &lds[16384], wave, lane);
  stage_half(Bb + 128 * K,      K, &lds[24576], wave, lane);
  stage_half(Ab + 64,           K, &lds[32768], wave, lane);
  stage_half(Ab + 128 * K + 64, K, &lds[40960], wave, lane);
  stage_half(Bb + 64,           K, &lds[49152], wave, lane);
  VM6; BAR;

  const int iters = NT >> 1;
  for (int i = 0; i < iters; ++i) {
    const int t0 = 2 * i;
    const bool nl = (i < iters - 1);
    // P1: reads a0-3,b0-1 (12); stage B1buf1(2i+1)
    RDA(0, 0, 3); RDB(0, 0, 1);
    stage_half(Bb + 128 * K + (t0 + 1) * 64, K, &lds[57344], wave, lane);
    BAR; LGKM0; QUAD(0, 0); BAR;
    // P2: reads a4-7 (8)
    RDA(0, 4, 7);
    BAR; LGKM0; QUAD(1, 0); BAR;
    // P3: reads b2-3 (4); stage A0buf0(2i+2)
    RDB(0, 2, 3);
    if (nl) stage_half(Ab + (t0 + 2) * 64, K, &lds[0], wave, lane);
    BAR; LGKM0; QUAD(0, 1); BAR;
    // P4: stage A1buf0(2i+2); vmcnt(4) => tile 2i+1 landed
    if (nl) stage_half(Ab + 128 * K + (t0 + 2) * 64, K, &lds[8192], wave, lane);
    BAR; QUAD(1, 1);
    if (nl) { VM4; } else { VM0; }
    BAR;
    // P5: reads buf1 a0-3,b0-1 (12); stage B0buf0(2i+2)
    RDA(32768, 0, 3); RDB(32768, 0, 1);
    if (nl) stage_half(Bb + (t0 + 2) * 64, K, &lds[16384], wave, lane);
    BAR; LGKM0; QUAD(0, 0); BAR;
    // P6: reads buf1 a4-7 (8); stage B1buf0(2i+2)
    RDA(32768, 4, 7);
    if (nl) stage_half(Bb + 128 * K + (t0 + 2) * 64, K, &lds[24576], wave, lane);
    BAR; LGKM0; QUAD(1, 0); BAR;
    // P7: reads buf1 b2-3 (4); stage A0buf1(2i+3)
    RDB(32768, 2, 3);
    if (nl) stage_half(Ab + (t0 + 3) * 64, K, &lds[32768], wave, lane);
    BAR; LGKM0; QUAD(0, 1); BAR;
    // P8: stage A1buf1(2i+3) + B0buf1(2i+3); vmcnt(6) => tile 2i+2 landed
    if (nl) {
      stage_half(Ab + 128 * K + (t0 + 3) * 64, K, &lds[40960], wave, lane);
      stage_half(Bb + (t0 + 3) * 64, K, &lds[49152], wave, lane);
    }
    BAR; QUAD(1, 1);
    if (nl) VM6;
    BAR;
  }

  const int lr = lane >> 4, lc = lane & 15;
  if (MODE == 2) {
#pragma unroll
    for (int mf = 0; mf < 8; ++mf) {
#pragma unroll
      for (int r = 0; r < 4; ++r) {
        const long grow = m0 + wm * 128 + mf * 16 + lr * 4 + r;
        const long bb = grow >> 4;
        float ds = 0.f, ks2 = 0.f;
#pragma unroll
        for (int nf = 0; nf < 4; ++nf) {
          const long col = n0 + wn * 64 + nf * 16 + lc;
          float kv = acc[mf][nf][r] + bias[col];
          ds += kv * qbuf[bb * ADIM + col];
          ks2 += kv * kv;
        }
#pragma unroll
        for (int m = 1; m < 16; m <<= 1) {
          ds += __shfl_xor(ds, m, 64);
          ks2 += __shfl_xor(ks2, m, 64);
        }
        if (lc == 0) {
          atomicAdd(&dotb[grow], ds);
          atomicAdd(&kn2b[grow], ks2);
        }
      }
    }
  } else if (MODE == 4) {
    float* base = (ksl == 0) ? dstF : PF;
#pragma unroll
    for (int mf = 0; mf < 8; ++mf) {
#pragma unroll
      for (int nf = 0; nf < 4; ++nf) {
        const long col = n0 + wn * 64 + nf * 16 + lc;
        if (col < Nreal) {
          const float bv_ = (ksl == 0) ? bias[col] : 0.f;
#pragma unroll
          for (int r = 0; r < 4; ++r) {
            const long row = m0 + wm * 128 + mf * 16 + lr * 4 + r;
            base[row * (long)ldc + col] = acc[mf][nf][r] + bv_;
          }
        }
      }
    }
  } else {
#pragma unroll
    for (int mf = 0; mf < 8; ++mf) {
#pragma unroll
      for (int nf = 0; nf < 4; ++nf) {
        const long col = n0 + wn * 64 + nf * 16 + lc;
        if (col < Nreal) {
          const float bv_ = bias[col];
#pragma unroll
          for (int r = 0; r < 4; ++r) {
            const long row = m0 + wm * 128 + mf * 16 + lr * 4 + r;
            float v = acc[mf][nf][r] + bv_;
            if (RELU) v = fmaxf(v, 0.f);
            if (MODE == 0) dstF[row * (long)ldc + col] = v;
            else           dstH[row * (long)ldc + col] = f2bf(v);
          }
        }
      }
    }
  }
}

// --- out += partial (split-K reduce) ----------------------------------------
__global__ void addf_k(float* __restrict__ out, const float* __restrict__ p) {
  const size_t i = ((size_t)blockIdx.x * 256 + threadIdx.x) * 4;
  float4 a = *(float4*)&out[i];
  float4 b = *(const float4*)&p[i];
  a.x += b.x; a.y += b.y; a.z += b.z; a.w += b.w;
  *(float4*)&out[i] = a;
}

// --- 128x128 2-phase GEMM (kept for z / q / fused) --------------------------
template <int MODE, bool RELU>
__global__ __launch_bounds__(256, 2)
void gemm_bt(const u16* __restrict__ A, const u16* __restrict__ BT,
             const float* __restrict__ bias, int K, int Nreal,
             float* __restrict__ dstF, u16* __restrict__ dstH, int ldc,
             int mt, int nt, int fastm) {
  __shared__ alignas(16) u16 Ash[128 * 64];
  __shared__ alignas(16) u16 Bsh[128 * 64];
  const int nwg = mt * nt;
  const int xcd = blockIdx.x & 7, idx = blockIdx.x >> 3;
  const int qq = nwg >> 3, rr = nwg & 7;
  const int wg = (xcd < rr ? xcd * (qq + 1) : rr * (qq + 1) + (xcd - rr) * qq) + idx;
  int tm, tn;
  if (fastm) { tm = wg % mt; tn = wg / mt; } else { tn = wg % nt; tm = wg / nt; }

  const int tid = threadIdx.x;
  const int wave = tid >> 6, lane = tid & 63;
  const long m0 = (long)tm * 128;
  const long n0 = (long)tn * 128;
  const int wm = wave >> 1, wnn = wave & 1;
  f32x4 acc[4][4] = {};

  const int srow = (wave << 5) + (lane >> 3);
  const int scol = (lane & 7) << 3;

  for (int k0 = 0; k0 < K; k0 += 64) {
    __syncthreads();
#pragma unroll
    for (int i = 0; i < 4; ++i) {
      const int r = srow + i * 8;
      gl_lds16(A + (m0 + r) * (long)K + k0 + scol, &Ash[r * 64 + scol]);
      gl_lds16(BT + (n0 + r) * (long)K + k0 + scol, &Bsh[r * 64 + scol]);
    }
    __syncthreads();
#pragma unroll
    for (int kb = 0; kb < 2; ++kb) {
      bf16x8 af[4], bfv[4];
#pragma unroll
      for (int f = 0; f < 4; ++f) {
        af[f]  = *(const bf16x8*)&Ash[(wm * 64 + f * 16 + (lane & 15)) * 64 + kb * 32 + (lane >> 4) * 8];
        bfv[f] = *(const bf16x8*)&Bsh[(wnn * 64 + f * 16 + (lane & 15)) * 64 + kb * 32 + (lane >> 4) * 8];
      }
#pragma unroll
      for (int mf = 0; mf < 4; ++mf)
#pragma unroll
        for (int nf = 0; nf < 4; ++nf)
          acc[mf][nf] = __builtin_amdgcn_mfma_f32_16x16x32_bf16(af[mf], bfv[nf], acc[mf][nf], 0, 0, 0);
    }
  }

  const int lr = lane >> 4, lc = lane & 15;
#pragma unroll
  for (int mf = 0; mf < 4; ++mf) {
#pragma unroll
    for (int nf = 0; nf < 4; ++nf) {
      const long col = n0 + wnn * 64 + nf * 16 + lc;
      if (col < Nreal) {
        const float bv_ = bias[col];
#pragma unroll
        for (int r = 0; r < 4; ++r) {
          const long row = m0 + wm * 64 + mf * 16 + lr * 4 + r;
          float v = acc[mf][nf][r] + bv_;
          if (RELU) v = fmaxf(v, 0.f);
          if (MODE == 0) dstF[row * (long)ldc + col] = v;
          else           dstH[row * (long)ldc + col] = f2bf(v);
        }
      }
    }
  }
}

// --- qn2[b] = |q[b,:]|^2 ----------------------------------------------------
__global__ void qnorm_k(const float* __restrict__ q, float* __restrict__ qn2) {
  const int b = blockIdx.x, t = threadIdx.x;
  const float4* row = (const float4*)(q + (size_t)b * ADIM);
  float s = 0.f;
#pragma unroll
  for (int i = 0; i < 2; ++i) {
    float4 v = row[t + i * 256];
    s += v.x * v.x + v.y * v.y + v.z * v.z + v.w * v.w;
  }
#pragma unroll
  for (int m = 1; m < 64; m <<= 1) s += __shfl_xor(s, m, 64);
  __shared__ float wsum[4];
  if ((t & 63) == 0) wsum[t >> 6] = s;
  __syncthreads();
  if (t == 0) qn2[b] = wsum[0] + wsum[1] + wsum[2] + wsum[3];
}

// --- per-row softmax of cs*ed, accumulate attn sums -------------------------
__global__ void attn_k(const float* __restrict__ dotb, const float* __restrict__ kn2b,
                       const float* __restrict__ qn2, float* __restrict__ asum) {
  const int b = blockIdx.x * 256 + threadIdx.x;
  const int lane = threadIdx.x & 63;
  const float q2 = qn2[b];
  const float qn = fmaxf(sqrtf(q2), 1e-8f);
  float lg[VIEW];
  float mx = -1e30f;
#pragma unroll
  for (int v = 0; v < VIEW; ++v) {
    const float d = dotb[b * VIEW + v], k2 = kn2b[b * VIEW + v];
    const float kn = fmaxf(sqrtf(k2), 1e-8f);
    const float cs = d / (qn * kn);
    const float ed = sqrtf(fmaxf(q2 - 2.f * d + k2, 0.f));
    lg[v] = cs * ed;
    mx = fmaxf(mx, lg[v]);
  }
  float s = 0.f;
#pragma unroll
  for (int v = 0; v < VIEW; ++v) { lg[v] = expf(lg[v] - mx); s += lg[v]; }
  const float inv = 1.f / s;
#pragma unroll
  for (int v = 0; v < VIEW; ++v) {
    float aa = lg[v] * inv;
#pragma unroll
    for (int m = 1; m < 64; m <<= 1) aa += __shfl_xor(aa, m, 64);
    if (lane == 0) atomicAdd(&asum[v], aa);
  }
}

// --- g~[b,w] = sum_v attn_mean[v]*gpt[b,v,w] (bf16 in, bf16 out) ------------
__global__ void gtilde_k(const u16* __restrict__ gpt, const float* __restrict__ asum,
                         u16* __restrict__ g) {
  const int b = blockIdx.x, t = threadIdx.x;  // 64 threads, 8 cols each
  float am[VIEW];
#pragma unroll
  for (int v = 0; v < VIEW; ++v) am[v] = asum[v] * (1.f / (float)BATCH);
  float s[8] = {};
  const u16* gx = gpt + (size_t)b * (VIEW * WEMB) + t * 8;
#pragma unroll
  for (int v = 0; v < VIEW; ++v) {
    bf16x8 gv = *(const bf16x8*)&gx[v * WEMB];
#pragma unroll
    for (int j = 0; j < 8; ++j) s[j] += am[v] * (float)gv[j];
  }
  ushort4 o0, o1;
  o0 = make_ushort4(f2bf(s[0]), f2bf(s[1]), f2bf(s[2]), f2bf(s[3]));
  o1 = make_ushort4(f2bf(s[4]), f2bf(s[5]), f2bf(s[6]), f2bf(s[7]));
  *(ushort4*)&g[(size_t)b * WEMB + t * 8] = o0;
  *(ushort4*)&g[(size_t)b * WEMB + t * 8 + 4] = o1;
}

// ---------------------------------------------------------------------------
extern "C" void kernel_launch(void* const* d_in, const int* in_sizes, int n_in,
                              void* d_out, int out_size, void* d_ws, size_t ws_size,
                              hipStream_t stream) {
  const float* x   = (const float*)d_in[0];
  const float* Wq  = (const float*)d_in[1];
  const float* bq  = (const float*)d_in[2];
  const float* Wk  = (const float*)d_in[3];
  const float* bk  = (const float*)d_in[4];
  const float* Wv  = (const float*)d_in[5];
  const float* bv  = (const float*)d_in[6];
  const float* Wm  = (const float*)d_in[7];
  const float* bm  = (const float*)d_in[8];
  const float* Wd1 = (const float*)d_in[9];
  const float* bd1 = (const float*)d_in[10];
  const float* Wd2 = (const float*)d_in[11];
  const float* bd2 = (const float*)d_in[12];
  float* out = (float*)d_out;

  char* ws = (char*)d_ws;
  size_t off = 0;
  auto alloc = [&](size_t bytes) -> void* {
    void* p = ws + off;
    off = (off + bytes + 255) & ~(size_t)255;
    return p;
  };
  u16* WqT  = (u16*)alloc((size_t)ADIM * WEMB * 2);
  u16* WkT  = (u16*)alloc((size_t)ADIM * WEMB * 2);
  u16* WvT  = (u16*)alloc((size_t)ADIM * WEMB * 2);
  u16* WmT  = (u16*)alloc((size_t)EMB * KCATP * 2);
  u16* Wd1T = (u16*)alloc((size_t)4096 * EMB * 2);
  u16* Wd2T = (u16*)alloc((size_t)NOUTP * 4096 * 2);
  // ---- dead-by-out arena: desc..z + pad. Byte audit:
  //   desc 2,097,152 + gpt 33,554,432 + cc 9,961,472 + q 16,777,216
  // + qn2 8,192 + stats 262,400 + gt 2,097,152 + z 8,388,608 = 73,146,624 B.
  //   Pout needs 2048*9016*4 = 73,859,072 B -> pad 1 MiB => 74,195,200 B. OK.
  u16* desc = (u16*)alloc((size_t)BATCH * WEMB * 2);
  u16* gpt  = (u16*)alloc((size_t)BATCH * VIEW * WEMB * 2);
  u16* cc   = (u16*)alloc((size_t)BATCH * KCATP * 2);
  float* q    = (float*)alloc((size_t)BATCH * ADIM * 4);
  float* qn2  = (float*)alloc((size_t)BATCH * 4);
  float* stats = (float*)alloc((size_t)(BATCH * VIEW * 2 + 64) * 4);
  float* dotb = stats;
  float* kn2b = stats + BATCH * VIEW;
  float* asum = stats + BATCH * VIEW * 2;
  u16* gt = (u16*)alloc((size_t)BATCH * WEMB * 2);
  u16* z  = (u16*)alloc((size_t)BATCH * EMB * 2);
  (void)alloc((size_t)1 << 20);   // pad so Pout fits strictly inside arena
  u16* h  = (u16*)alloc((size_t)BATCH * 4096 * 2);
  if (off > ws_size) return;  // workspace too small -> clean validation fail
  float* Pout = (float*)desc;   // 73,859,072 B <= arena 74,195,200 B (audited)

  hipMemsetAsync(stats, 0, (size_t)(BATCH * VIEW * 2 + 64) * 4, stream);

  castx_k<<<BATCH, 256, 0, stream>>>(x, cc, desc, gpt);

  // fused transpose-cast of all 6 weights (one launch); tiles cover Kp x Np
  TcArgs ta;
  int base = 0;
  auto setd = [&](int i, const float* s, u16* d, int K, int N, int Kp, int Np) {
    ta.d[i] = TcDesc{s, d, K, N, Kp, Np, (Np + 63) / 64, base};
    base += ((Np + 63) / 64) * ((Kp + 63) / 64);
  };
  setd(0, Wq, WqT, WEMB, ADIM, WEMB, ADIM);
  setd(1, Wk, WkT, WEMB, ADIM, WEMB, ADIM);
  setd(2, Wv, WvT, WEMB, ADIM, WEMB, ADIM);
  setd(3, Wm, WmT, KCAT, EMB, KCATP, EMB);
  setd(4, Wd1, Wd1T, EMB, 4096, EMB, 4096);
  setd(5, Wd2, Wd2T, 4096, NOUT, 4096, NOUTP);
  transcast6_k<<<base, 256, 0, stream>>>(ta);

  // q = desc @ Wq + bq (fp32 out), 128^2, grid 256, N-fast
  gemm_bt<0, false><<<16 * 16, 256, 0, stream>>>(
      desc, WqT, bq, WEMB, ADIM, q, nullptr, ADIM, BATCH / 128, ADIM / 128, 0);
  qnorm_k<<<BATCH, 256, 0, stream>>>(q, qn2);
  // kstats: 256^2 8-phase, grid 1024 (= exactly 4 rounds), N-fast
  gemm256<2, false><<<128 * 8, 512, 0, stream>>>(
      gpt, WkT, bk, WEMB, ADIM, nullptr, nullptr, nullptr, 0, q, dotb, kn2b,
      BATCH * VIEW / 256, ADIM / 256, 0, 1, WEMB);
  attn_k<<<BATCH / 256, 256, 0, stream>>>(dotb, kn2b, qn2, asum);
  gtilde_k<<<BATCH, 64, 0, stream>>>(gpt, asum, gt);
  // fused = g~ @ Wv + bv -> concat cols [312, 2360), 128^2
  gemm_bt<1, false><<<16 * 16, 256, 0, stream>>>(
      gt, WvT, bv, WEMB, ADIM, nullptr, cc + ATT, KCATP, BATCH / 128, ADIM / 128, 0);
  // z = relu(concat @ Wm + bm), 128^2 grid 256
  gemm_bt<1, true><<<16 * 16, 256, 0, stream>>>(
      cc, WmT, bm, KCATP, EMB, nullptr, z, EMB, BATCH / 128, EMB / 128, 0);
  // h = relu(z @ Wd1 + bd1), 256^2 8-phase, grid 128, M-fast (share B panel)
  gemm256<1, true><<<8 * 16, 512, 0, stream>>>(
      z, Wd1T, bd1, EMB, 4096, nullptr, h, nullptr, 4096, nullptr, nullptr, nullptr,
      BATCH / 256, 4096 / 256, 1, 1, EMB);
  // out = h @ Wd2 + bd2: split-K=2 (grid 576, 75% pack), slice0->out (+bias),
  // slice1->Pout; then out += Pout.
  gemm256<4, false><<<8 * 36 * 2, 512, 0, stream>>>(
      h, Wd2T, bd2, 4096, NOUT, out, nullptr, Pout, NOUT, nullptr, nullptr, nullptr,
      BATCH / 256, NOUTP / 256, 1, 2, 2048);
  addf_k<<<(BATCH * NOUT) / 1024, 256, 0, stream>>>(out, Pout);
}

// Round 8
// 658.357 us; speedup vs baseline: 1.4754x; 1.0487x over previous
//
#include <hip/hip_runtime.h>

// ---------------------------------------------------------------------------
// CONTEXTUAL_AUTOENCODER: B=2048, IN=9016 (att 312 | desc 512 | gpt 16x512)
//   q = desc@Wq+bq; kstats from gpt@Wk+bk epilogue; softmax -> attn_mean;
//   g~ = sum_v am[v]*gpt -> fused = g~@Wv+bv; z,h,out MLP.
// R3: 256x256 8-phase GEMM (T2 swizzle + counted vmcnt + setprio).
// R4: FAILED split-K fp32 atomics (288MB RMW). R5: balanced ledger (null).
// R6: FAILED arena overrun (712KB into h). R7: split-K=2 + partial: net ~0
//     (Pout traffic ate the packing gain).
// R8: asymmetric tail split: out = zoneA 256 full-K tiles (exact round) +
//     zoneB 32 tail tiles split K=8 (256 blk) w/ 7x8MB partials + tailred;
//     h split-K=2 grid 256 exact round, slice1->Ph, relu(h+Ph) in place.
// ---------------------------------------------------------------------------

typedef __bf16 bf16x8 __attribute__((ext_vector_type(8)));
typedef float  f32x4  __attribute__((ext_vector_type(4)));
typedef unsigned short u16;

#define ATT   312
#define WEMB  512
#define VIEW  16
#define ADIM  2048
#define EMB   2048
#define BATCH 2048
#define INDIM 9016
#define KCAT  2360
#define KCATP 2432
#define NOUT  9016
#define NOUTP 9216   // 36 x 256 tiles; tail tiles tn 32..35 = cols 8192..9215

__device__ __forceinline__ u16 f2bf(float f) {
  unsigned u = __builtin_bit_cast(unsigned, f);
  u += 0x7FFFu + ((u >> 16) & 1u);            // RNE
  return (u16)(u >> 16);
}
__device__ __forceinline__ float bf2f(u16 b) {
  unsigned u = (unsigned)b << 16;
  return __builtin_bit_cast(float, u);
}

__device__ __forceinline__ void gl_lds16(const u16* g, u16* l) {
  __builtin_amdgcn_global_load_lds((const __attribute__((address_space(1))) void*)g,
                                   (__attribute__((address_space(3))) void*)l, 16, 0, 0);
}

// --- cast x into concat-att cols (+zero pad), desc, gpt (bf16) --------------
__global__ void castx_k(const float* __restrict__ x, u16* __restrict__ cc,
                        u16* __restrict__ desc, u16* __restrict__ gpt) {
  const int b = blockIdx.x, t = threadIdx.x;
  const float4* row = (const float4*)(x + (size_t)b * INDIM);
  for (int c = t; c < INDIM / 4; c += 256) {
    float4 v = row[c];
    ushort4 o = make_ushort4(f2bf(v.x), f2bf(v.y), f2bf(v.z), f2bf(v.w));
    if (c < ATT / 4)                 *(ushort4*)&cc[(size_t)b * KCATP + c * 4] = o;
    else if (c < (ATT + WEMB) / 4)   *(ushort4*)&desc[(size_t)b * WEMB + (c - ATT / 4) * 4] = o;
    else                             *(ushort4*)&gpt[(size_t)b * (VIEW * WEMB) + (c - (ATT + WEMB) / 4) * 4] = o;
  }
  if (t < (KCATP - KCAT) / 4) {
    *(ushort4*)&cc[(size_t)b * KCATP + KCAT + t * 4] = make_ushort4(0, 0, 0, 0);
  }
}

// --- fused transpose-cast of all 6 weights: src[K][N] f32 -> dst[Np][Kp] ----
struct TcDesc { const float* src; u16* dst; int K, N, Kp, Np, ntx, base; };
struct TcArgs { TcDesc d[6]; };

__global__ void transcast6_k(TcArgs A) {
  __shared__ float tile[64][65];
  int mi = 0;
  const int bid = blockIdx.x;
#pragma unroll
  for (int i = 1; i < 6; ++i) if (bid >= A.d[i].base) mi = i;
  const TcDesc& D = A.d[mi];
  const int local = bid - D.base;
  const int n0 = (local % D.ntx) * 64, k0 = (local / D.ntx) * 64;
  const int t = threadIdx.x;
  const int tr = t >> 4, tc4 = (t & 15) * 4;
#pragma unroll
  for (int i = 0; i < 4; ++i) {
    const int k = k0 + tr + i * 16;
    float v0 = 0.f, v1 = 0.f, v2 = 0.f, v3 = 0.f;
    if (k < D.K) {
      const int n = n0 + tc4;
      const float* p = D.src + (size_t)k * D.N + n;
      if (n + 3 < D.N) { float4 v = *(const float4*)p; v0 = v.x; v1 = v.y; v2 = v.z; v3 = v.w; }
      else {
        if (n + 0 < D.N) v0 = p[0];
        if (n + 1 < D.N) v1 = p[1];
        if (n + 2 < D.N) v2 = p[2];
        if (n + 3 < D.N) v3 = p[3];
      }
    }
    tile[tr + i * 16][tc4 + 0] = v0;
    tile[tr + i * 16][tc4 + 1] = v1;
    tile[tr + i * 16][tc4 + 2] = v2;
    tile[tr + i * 16][tc4 + 3] = v3;
  }
  __syncthreads();
#pragma unroll
  for (int i = 0; i < 4; ++i) {
    const int rn = tr + i * 16;
    const int n = n0 + rn;
    const int kk = k0 + tc4;
    if (n < D.Np && kk < D.Kp) {
      const bool nv = (n < D.N);
      ushort4 o = make_ushort4(f2bf(nv ? tile[tc4 + 0][rn] : 0.f),
                               f2bf(nv ? tile[tc4 + 1][rn] : 0.f),
                               f2bf(nv ? tile[tc4 + 2][rn] : 0.f),
                               f2bf(nv ? tile[tc4 + 3][rn] : 0.f));
      *(ushort4*)&D.dst[(size_t)n * D.Kp + kk] = o;
    }
  }
}

// ===========================================================================
// 256x256 8-phase GEMM (R5 balanced ledger).
// MODE 2: kstats epilogue (generic mt/nt decode).
// MODE 5: out two-zone: blk<256 -> zoneA full-K tile (M-fast over 8x32),
//         direct fp32+bias; blk>=256 -> zoneB tail tile (tn 32..35) split
//         K=8x512; ksl 0 -> fp32+bias, ksl>=1 -> Pt[ksl-1][2048][1024].
// MODE 6: h split-K=2 (grid 256): ksl 0 -> bf16 store +bias (no relu),
//         ksl 1 -> fp32 partial PF.
// ===========================================================================
__device__ __forceinline__ void stage_half(const u16* __restrict__ src, int ld,
                                           u16* dst, int wave, int lane) {
#pragma unroll
  for (int j = 0; j < 2; ++j) {
    const int s = wave * 2 + j;                    // subtile 0..15
    const int r = ((s >> 1) << 4) + (lane >> 2);   // logical row in half
    const int c = ((s & 1) << 5) +
                  (((lane & 3) << 3) ^ (((lane >> 5) & 1) << 4));  // inv-swz col
    gl_lds16(src + (long)r * ld + c, dst + s * 512 + (lane << 3));
  }
}

#define BAR   __builtin_amdgcn_s_barrier()
#define LGKM0 asm volatile("s_waitcnt lgkmcnt(0)" ::: "memory")
#define VM6   asm volatile("s_waitcnt vmcnt(6)" ::: "memory")
#define VM4   asm volatile("s_waitcnt vmcnt(4)" ::: "memory")
#define VM0   asm volatile("s_waitcnt vmcnt(0)" ::: "memory")

#define RDA(bufo, lo, hi) do { _Pragma("unroll") for (int mf = (lo); mf <= (hi); ++mf) \
  _Pragma("unroll") for (int kk = 0; kk < 2; ++kk) \
    a[mf][kk] = *(const bf16x8*)&lds[(bufo) + aoff0 + (mf * 2 + kk) * 512]; } while (0)
#define RDB(bufo, lo, hi) do { _Pragma("unroll") for (int nf = (lo); nf <= (hi); ++nf) \
  _Pragma("unroll") for (int kk = 0; kk < 2; ++kk) \
    b[nf][kk] = *(const bf16x8*)&lds[(bufo) + boff0 + nf * 1024 + kk * 512]; } while (0)
#define QUAD(qm, qn) do { __builtin_amdgcn_s_setprio(1); \
  _Pragma("unroll") for (int m4 = 0; m4 < 4; ++m4) \
  _Pragma("unroll") for (int n2 = 0; n2 < 2; ++n2) \
  _Pragma("unroll") for (int kk = 0; kk < 2; ++kk) \
    acc[(qm) * 4 + m4][(qn) * 2 + n2] = __builtin_amdgcn_mfma_f32_16x16x32_bf16( \
        a[(qm) * 4 + m4][kk], b[(qn) * 2 + n2][kk], acc[(qm) * 4 + m4][(qn) * 2 + n2], 0, 0, 0); \
  __builtin_amdgcn_s_setprio(0); } while (0)

template <int MODE>
__global__ __launch_bounds__(512, 2)
void gemm256(const u16* __restrict__ A, const u16* __restrict__ BT,
             const float* __restrict__ bias, int K, int Nreal,
             float* __restrict__ dstF, u16* __restrict__ dstH,
             float* __restrict__ PF, int ldc,
             const float* __restrict__ qbuf, float* __restrict__ dotb,
             float* __restrict__ kn2b, int mt, int nt, int fastm) {
  __shared__ alignas(16) u16 lds[65536];   // 128 KB
  int tm, tn, ksl = 0, kloc = K;
  long koff = 0;
  if (MODE == 5) {
    if ((int)blockIdx.x < 256) {           // zone A: 256 full-K tiles
      const int w = ((blockIdx.x & 7) << 5) + (blockIdx.x >> 3);
      tm = w & 7; tn = w >> 3;             // tn 0..31
    } else {                               // zone B: 32 tail tiles x 8 slices
      const int b2 = blockIdx.x - 256;
      const int w = ((b2 & 7) << 5) + (b2 >> 3);
      const int tile = w >> 3; ksl = w & 7;
      tm = tile & 7; tn = 32 + (tile >> 3);
      kloc = 512; koff = (long)ksl * 512;
    }
  } else if (MODE == 6) {                  // h: 128 tiles x 2 slices
    const int w = ((blockIdx.x & 7) << 5) + (blockIdx.x >> 3);
    ksl = w & 1;
    const int tile = w >> 1;
    tm = tile & 7; tn = tile >> 3;         // mt=8, nt=16, M-fast
    kloc = K >> 1; koff = (long)ksl * kloc;
  } else {                                 // generic (kstats)
    const int nwg = mt * nt;
    const int xcd = blockIdx.x & 7, idx = blockIdx.x >> 3;
    const int qq = nwg >> 3, rr = nwg & 7;
    const int wg = (xcd < rr ? xcd * (qq + 1) : rr * (qq + 1) + (xcd - rr) * qq) + idx;
    if (fastm) { tm = wg % mt; tn = wg / mt; } else { tn = wg % nt; tm = wg / nt; }
  }

  const int tid = threadIdx.x;
  const int wave = tid >> 6, lane = tid & 63;
  const long m0 = (long)tm * 256, n0 = (long)tn * 256;
  const int wm = wave >> 2, wn = wave & 3;          // 2 x 4 wave grid
  const u16* Ab = A + m0 * K + koff;
  const u16* Bb = BT + n0 * K + koff;

  f32x4 acc[8][4] = {};
  bf16x8 a[8][2], b[4][2];
  const int LP = (lane & 15) * 32 + ((((lane >> 4) << 3)) ^ (((lane >> 3) & 1) << 4));
  const int aoff0 = wm * 8192 + LP;
  const int boff0 = 16384 + (wn >> 1) * 8192 + (wn & 1) * 4096 + LP;
  const int NT = kloc >> 6;

  // prologue: buf0 tile0 (4 halves) + buf1 tile1 {A0,A1,B0}
  stage_half(Ab,                K, &lds[0],     wave, lane);
  stage_half(Ab + 128 * K,      K, &lds[8192],  wave, lane);
  stage_half(Bb,                K, &lds[16384], wave, lane);
  stage_half(Bb + 128 * K,      K, &lds[24576], wave, lane);
  stage_half(Ab + 64,           K, &lds[32768], wave, lane);
  stage_half(Ab + 128 * K + 64, K, &lds[40960], wave, lane);
  stage_half(Bb + 64,           K, &lds[49152], wave, lane);
  VM6; BAR;

  const int iters = NT >> 1;
  for (int i = 0; i < iters; ++i) {
    const int t0 = 2 * i;
    const bool nl = (i < iters - 1);
    // P1: reads a0-3,b0-1 (12); stage B1buf1(2i+1)
    RDA(0, 0, 3); RDB(0, 0, 1);
    stage_half(Bb + 128 * K + (t0 + 1) * 64, K, &lds[57344], wave, lane);
    BAR; LGKM0; QUAD(0, 0); BAR;
    // P2: reads a4-7 (8)
    RDA(0, 4, 7);
    BAR; LGKM0; QUAD(1, 0); BAR;
    // P3: reads b2-3 (4); stage A0buf0(2i+2)
    RDB(0, 2, 3);
    if (nl) stage_half(Ab + (t0 + 2) * 64, K, &lds[0], wave, lane);
    BAR; LGKM0; QUAD(0, 1); BAR;
    // P4: stage A1buf0(2i+2); vmcnt(4) => tile 2i+1 landed
    if (nl) stage_half(Ab + 128 * K + (t0 + 2) * 64, K, &lds[8192], wave, lane);
    BAR; QUAD(1, 1);
    if (nl) { VM4; } else { VM0; }
    BAR;
    // P5: reads buf1 a0-3,b0-1 (12); stage B0buf0(2i+2)
    RDA(32768, 0, 3); RDB(32768, 0, 1);
    if (nl) stage_half(Bb + (t0 + 2) * 64, K, &lds[16384], wave, lane);
    BAR; LGKM0; QUAD(0, 0); BAR;
    // P6: reads buf1 a4-7 (8); stage B1buf0(2i+2)
    RDA(32768, 4, 7);
    if (nl) stage_half(Bb + 128 * K + (t0 + 2) * 64, K, &lds[24576], wave, lane);
    BAR; LGKM0; QUAD(1, 0); BAR;
    // P7: reads buf1 b2-3 (4); stage A0buf1(2i+3)
    RDB(32768, 2, 3);
    if (nl) stage_half(Ab + (t0 + 3) * 64, K, &lds[32768], wave, lane);
    BAR; LGKM0; QUAD(0, 1); BAR;
    // P8: stage A1buf1(2i+3) + B0buf1(2i+3); vmcnt(6) => tile 2i+2 landed
    if (nl) {
      stage_half(Ab + 128 * K + (t0 + 3) * 64, K, &lds[40960], wave, lane);
      stage_half(Bb + (t0 + 3) * 64, K, &lds[49152], wave, lane);
    }
    BAR; QUAD(1, 1);
    if (nl) VM6;
    BAR;
  }

  const int lr = lane >> 4, lc = lane & 15;
  if (MODE == 2) {
#pragma unroll
    for (int mf = 0; mf < 8; ++mf) {
#pragma unroll
      for (int r = 0; r < 4; ++r) {
        const long grow = m0 + wm * 128 + mf * 16 + lr * 4 + r;
        const long bb = grow >> 4;
        float ds = 0.f, ks2 = 0.f;
#pragma unroll
        for (int nf = 0; nf < 4; ++nf) {
          const long col = n0 + wn * 64 + nf * 16 + lc;
          float kv = acc[mf][nf][r] + bias[col];
          ds += kv * qbuf[bb * ADIM + col];
          ks2 += kv * kv;
        }
#pragma unroll
        for (int m = 1; m < 16; m <<= 1) {
          ds += __shfl_xor(ds, m, 64);
          ks2 += __shfl_xor(ks2, m, 64);
        }
        if (lc == 0) {
          atomicAdd(&dotb[grow], ds);
          atomicAdd(&kn2b[grow], ks2);
        }
      }
    }
  } else if (MODE == 5) {
    if (ksl == 0) {
#pragma unroll
      for (int mf = 0; mf < 8; ++mf) {
#pragma unroll
        for (int nf = 0; nf < 4; ++nf) {
          const long col = n0 + wn * 64 + nf * 16 + lc;
          if (col < Nreal) {
            const float bv_ = bias[col];
#pragma unroll
            for (int r = 0; r < 4; ++r) {
              const long row = m0 + wm * 128 + mf * 16 + lr * 4 + r;
              dstF[row * (long)ldc + col] = acc[mf][nf][r] + bv_;
            }
          }
        }
      }
    } else {
      float* pt = PF + (long)(ksl - 1) * BATCH * 1024;
#pragma unroll
      for (int mf = 0; mf < 8; ++mf) {
#pragma unroll
        for (int nf = 0; nf < 4; ++nf) {
          const long col = n0 + wn * 64 + nf * 16 + lc;   // 8192..9215
#pragma unroll
          for (int r = 0; r < 4; ++r) {
            const long row = m0 + wm * 128 + mf * 16 + lr * 4 + r;
            pt[row * 1024 + (col - 8192)] = acc[mf][nf][r];
          }
        }
      }
    }
  } else {  // MODE 6
#pragma unroll
    for (int mf = 0; mf < 8; ++mf) {
#pragma unroll
      for (int nf = 0; nf < 4; ++nf) {
        const long col = n0 + wn * 64 + nf * 16 + lc;
        const float bv_ = bias[col];
#pragma unroll
        for (int r = 0; r < 4; ++r) {
          const long row = m0 + wm * 128 + mf * 16 + lr * 4 + r;
          if (ksl == 0) dstH[row * (long)ldc + col] = f2bf(acc[mf][nf][r] + bv_);
          else          PF[row * (long)ldc + col] = acc[mf][nf][r];
        }
      }
    }
  }
}

// --- h = relu(h + Ph) in place (bf16 h, fp32 Ph) ----------------------------
__global__ void relucast2_k(u16* __restrict__ h, const float* __restrict__ ph) {
  const size_t i = ((size_t)blockIdx.x * 256 + threadIdx.x) * 8;
  bf16x8 hv = *(const bf16x8*)&h[i];
  float4 pa = *(const float4*)&ph[i];
  float4 pb = *(const float4*)&ph[i + 4];
  ushort4 o0 = make_ushort4(f2bf(fmaxf((float)hv[0] + pa.x, 0.f)),
                            f2bf(fmaxf((float)hv[1] + pa.y, 0.f)),
                            f2bf(fmaxf((float)hv[2] + pa.z, 0.f)),
                            f2bf(fmaxf((float)hv[3] + pa.w, 0.f)));
  ushort4 o1 = make_ushort4(f2bf(fmaxf((float)hv[4] + pb.x, 0.f)),
                            f2bf(fmaxf((float)hv[5] + pb.y, 0.f)),
                            f2bf(fmaxf((float)hv[6] + pb.z, 0.f)),
                            f2bf(fmaxf((float)hv[7] + pb.w, 0.f)));
  *(ushort4*)&h[i] = o0;
  *(ushort4*)&h[i + 4] = o1;
}

// --- out tail reduce: out[r][8192+c] += sum_s Pt[s][r][c], c in [0,824) -----
__global__ void tailred_k(float* __restrict__ out, const float* __restrict__ pt) {
  const int i = blockIdx.x * 256 + threadIdx.x;   // 2048 rows x 206 float4
  const int row = i / 206, c = (i % 206) * 4;
  float4 acc = *(float4*)&out[(size_t)row * NOUT + 8192 + c];
#pragma unroll
  for (int s = 0; s < 7; ++s) {
    float4 p = *(const float4*)&pt[(size_t)s * BATCH * 1024 + (size_t)row * 1024 + c];
    acc.x += p.x; acc.y += p.y; acc.z += p.z; acc.w += p.w;
  }
  *(float4*)&out[(size_t)row * NOUT + 8192 + c] = acc;
}

// --- 128x128 2-phase GEMM (kept for z / q / fused) --------------------------
template <int MODE, bool RELU>
__global__ __launch_bounds__(256, 2)
void gemm_bt(const u16* __restrict__ A, const u16* __restrict__ BT,
             const float* __restrict__ bias, int K, int Nreal,
             float* __restrict__ dstF, u16* __restrict__ dstH, int ldc,
             int mt, int nt, int fastm) {
  __shared__ alignas(16) u16 Ash[128 * 64];
  __shared__ alignas(16) u16 Bsh[128 * 64];
  const int nwg = mt * nt;
  const int xcd = blockIdx.x & 7, idx = blockIdx.x >> 3;
  const int qq = nwg >> 3, rr = nwg & 7;
  const int wg = (xcd < rr ? xcd * (qq + 1) : rr * (qq + 1) + (xcd - rr) * qq) + idx;
  int tm, tn;
  if (fastm) { tm = wg % mt; tn = wg / mt; } else { tn = wg % nt; tm = wg / nt; }

  const int tid = threadIdx.x;
  const int wave = tid >> 6, lane = tid & 63;
  const long m0 = (long)tm * 128;
  const long n0 = (long)tn * 128;
  const int wm = wave >> 1, wnn = wave & 1;
  f32x4 acc[4][4] = {};

  const int srow = (wave << 5) + (lane >> 3);
  const int scol = (lane & 7) << 3;

  for (int k0 = 0; k0 < K; k0 += 64) {
    __syncthreads();
#pragma unroll
    for (int i = 0; i < 4; ++i) {
      const int r = srow + i * 8;
      gl_lds16(A + (m0 + r) * (long)K + k0 + scol, &Ash[r * 64 + scol]);
      gl_lds16(BT + (n0 + r) * (long)K + k0 + scol, &Bsh[r * 64 + scol]);
    }
    __syncthreads();
#pragma unroll
    for (int kb = 0; kb < 2; ++kb) {
      bf16x8 af[4], bfv[4];
#pragma unroll
      for (int f = 0; f < 4; ++f) {
        af[f]  = *(const bf16x8*)&Ash[(wm * 64 + f * 16 + (lane & 15)) * 64 + kb * 32 + (lane >> 4) * 8];
        bfv[f] = *(const bf16x8*)&Bsh[(wnn * 64 + f * 16 + (lane & 15)) * 64 + kb * 32 + (lane >> 4) * 8];
      }
#pragma unroll
      for (int mf = 0; mf < 4; ++mf)
#pragma unroll
        for (int nf = 0; nf < 4; ++nf)
          acc[mf][nf] = __builtin_amdgcn_mfma_f32_16x16x32_bf16(af[mf], bfv[nf], acc[mf][nf], 0, 0, 0);
    }
  }

  const int lr = lane >> 4, lc = lane & 15;
#pragma unroll
  for (int mf = 0; mf < 4; ++mf) {
#pragma unroll
    for (int nf = 0; nf < 4; ++nf) {
      const long col = n0 + wnn * 64 + nf * 16 + lc;
      if (col < Nreal) {
        const float bv_ = bias[col];
#pragma unroll
        for (int r = 0; r < 4; ++r) {
          const long row = m0 + wm * 64 + mf * 16 + lr * 4 + r;
          float v = acc[mf][nf][r] + bv_;
          if (RELU) v = fmaxf(v, 0.f);
          if (MODE == 0) dstF[row * (long)ldc + col] = v;
          else           dstH[row * (long)ldc + col] = f2bf(v);
        }
      }
    }
  }
}

// --- qn2[b] = |q[b,:]|^2 ----------------------------------------------------
__global__ void qnorm_k(const float* __restrict__ q, float* __restrict__ qn2) {
  const int b = blockIdx.x, t = threadIdx.x;
  const float4* row = (const float4*)(q + (size_t)b * ADIM);
  float s = 0.f;
#pragma unroll
  for (int i = 0; i < 2; ++i) {
    float4 v = row[t + i * 256];
    s += v.x * v.x + v.y * v.y + v.z * v.z + v.w * v.w;
  }
#pragma unroll
  for (int m = 1; m < 64; m <<= 1) s += __shfl_xor(s, m, 64);
  __shared__ float wsum[4];
  if ((t & 63) == 0) wsum[t >> 6] = s;
  __syncthreads();
  if (t == 0) qn2[b] = wsum[0] + wsum[1] + wsum[2] + wsum[3];
}

// --- per-row softmax of cs*ed, accumulate attn sums -------------------------
__global__ void attn_k(const float* __restrict__ dotb, const float* __restrict__ kn2b,
                       const float* __restrict__ qn2, float* __restrict__ asum) {
  const int b = blockIdx.x * 256 + threadIdx.x;
  const int lane = threadIdx.x & 63;
  const float q2 = qn2[b];
  const float qn = fmaxf(sqrtf(q2), 1e-8f);
  float lg[VIEW];
  float mx = -1e30f;
#pragma unroll
  for (int v = 0; v < VIEW; ++v) {
    const float d = dotb[b * VIEW + v], k2 = kn2b[b * VIEW + v];
    const float kn = fmaxf(sqrtf(k2), 1e-8f);
    const float cs = d / (qn * kn);
    const float ed = sqrtf(fmaxf(q2 - 2.f * d + k2, 0.f));
    lg[v] = cs * ed;
    mx = fmaxf(mx, lg[v]);
  }
  float s = 0.f;
#pragma unroll
  for (int v = 0; v < VIEW; ++v) { lg[v] = expf(lg[v] - mx); s += lg[v]; }
  const float inv = 1.f / s;
#pragma unroll
  for (int v = 0; v < VIEW; ++v) {
    float aa = lg[v] * inv;
#pragma unroll
    for (int m = 1; m < 64; m <<= 1) aa += __shfl_xor(aa, m, 64);
    if (lane == 0) atomicAdd(&asum[v], aa);
  }
}

// --- g~[b,w] = sum_v attn_mean[v]*gpt[b,v,w] (bf16 in, bf16 out) ------------
__global__ void gtilde_k(const u16* __restrict__ gpt, const float* __restrict__ asum,
                         u16* __restrict__ g) {
  const int b = blockIdx.x, t = threadIdx.x;  // 64 threads, 8 cols each
  float am[VIEW];
#pragma unroll
  for (int v = 0; v < VIEW; ++v) am[v] = asum[v] * (1.f / (float)BATCH);
  float s[8] = {};
  const u16* gx = gpt + (size_t)b * (VIEW * WEMB) + t * 8;
#pragma unroll
  for (int v = 0; v < VIEW; ++v) {
    bf16x8 gv = *(const bf16x8*)&gx[v * WEMB];
#pragma unroll
    for (int j = 0; j < 8; ++j) s[j] += am[v] * (float)gv[j];
  }
  ushort4 o0, o1;
  o0 = make_ushort4(f2bf(s[0]), f2bf(s[1]), f2bf(s[2]), f2bf(s[3]));
  o1 = make_ushort4(f2bf(s[4]), f2bf(s[5]), f2bf(s[6]), f2bf(s[7]));
  *(ushort4*)&g[(size_t)b * WEMB + t * 8] = o0;
  *(ushort4*)&g[(size_t)b * WEMB + t * 8 + 4] = o1;
}

// ---------------------------------------------------------------------------
extern "C" void kernel_launch(void* const* d_in, const int* in_sizes, int n_in,
                              void* d_out, int out_size, void* d_ws, size_t ws_size,
                              hipStream_t stream) {
  const float* x   = (const float*)d_in[0];
  const float* Wq  = (const float*)d_in[1];
  const float* bq  = (const float*)d_in[2];
  const float* Wk  = (const float*)d_in[3];
  const float* bk  = (const float*)d_in[4];
  const float* Wv  = (const float*)d_in[5];
  const float* bv  = (const float*)d_in[6];
  const float* Wm  = (const float*)d_in[7];
  const float* bm  = (const float*)d_in[8];
  const float* Wd1 = (const float*)d_in[9];
  const float* bd1 = (const float*)d_in[10];
  const float* Wd2 = (const float*)d_in[11];
  const float* bd2 = (const float*)d_in[12];
  float* out = (float*)d_out;

  char* ws = (char*)d_ws;
  size_t off = 0;
  auto alloc = [&](size_t bytes) -> void* {
    void* p = ws + off;
    off = (off + bytes + 255) & ~(size_t)255;
    return p;
  };
  u16* WqT  = (u16*)alloc((size_t)ADIM * WEMB * 2);
  u16* WkT  = (u16*)alloc((size_t)ADIM * WEMB * 2);
  u16* WvT  = (u16*)alloc((size_t)ADIM * WEMB * 2);
  u16* WmT  = (u16*)alloc((size_t)EMB * KCATP * 2);
  u16* Wd1T = (u16*)alloc((size_t)4096 * EMB * 2);
  u16* Wd2T = (u16*)alloc((size_t)NOUTP * 4096 * 2);
  // ---- arena (aliased scratch). Byte audit:
  //   desc 2,097,152 + gpt 33,554,432 + cc 9,961,472 + q 16,777,216
  // + qn2 8,192 + stats 262,400 + gt 2,097,152 + z 8,388,608 = 73,146,624 B.
  //   Ph  (h partial, 2048*4096*4 = 33,554,432) aliases [0, 33.6MB): desc+gpt
  //     (both dead at h-GEMM; z at 64.76MB+ untouched).                  OK
  //   Ptail (7*2048*1024*4 = 58,720,256) aliases [0, 58.8MB): all dead
  //     at out-GEMM time (only h + Wd2T live, both outside).             OK
  u16* desc = (u16*)alloc((size_t)BATCH * WEMB * 2);
  u16* gpt  = (u16*)alloc((size_t)BATCH * VIEW * WEMB * 2);
  u16* cc   = (u16*)alloc((size_t)BATCH * KCATP * 2);
  float* q    = (float*)alloc((size_t)BATCH * ADIM * 4);
  float* qn2  = (float*)alloc((size_t)BATCH * 4);
  float* stats = (float*)alloc((size_t)(BATCH * VIEW * 2 + 64) * 4);
  float* dotb = stats;
  float* kn2b = stats + BATCH * VIEW;
  float* asum = stats + BATCH * VIEW * 2;
  u16* gt = (u16*)alloc((size_t)BATCH * WEMB * 2);
  u16* z  = (u16*)alloc((size_t)BATCH * EMB * 2);
  u16* h  = (u16*)alloc((size_t)BATCH * 4096 * 2);
  if (off > ws_size) return;  // workspace too small -> clean validation fail
  float* Ph    = (float*)desc;   // 33,554,432 B <= desc+gpt 35,651,584 B
  float* Ptail = (float*)desc;   // 58,720,256 B <= arena 73,146,624 B

  hipMemsetAsync(stats, 0, (size_t)(BATCH * VIEW * 2 + 64) * 4, stream);

  castx_k<<<BATCH, 256, 0, stream>>>(x, cc, desc, gpt);

  // fused transpose-cast of all 6 weights (one launch); tiles cover Kp x Np
  TcArgs ta;
  int base = 0;
  auto setd = [&](int i, const float* s, u16* d, int K, int N, int Kp, int Np) {
    ta.d[i] = TcDesc{s, d, K, N, Kp, Np, (Np + 63) / 64, base};
    base += ((Np + 63) / 64) * ((Kp + 63) / 64);
  };
  setd(0, Wq, WqT, WEMB, ADIM, WEMB, ADIM);
  setd(1, Wk, WkT, WEMB, ADIM, WEMB, ADIM);
  setd(2, Wv, WvT, WEMB, ADIM, WEMB, ADIM);
  setd(3, Wm, WmT, KCAT, EMB, KCATP, EMB);
  setd(4, Wd1, Wd1T, EMB, 4096, EMB, 4096);
  setd(5, Wd2, Wd2T, 4096, NOUT, 4096, NOUTP);
  transcast6_k<<<base, 256, 0, stream>>>(ta);

  // q = desc @ Wq + bq (fp32 out), 128^2, grid 256, N-fast
  gemm_bt<0, false><<<16 * 16, 256, 0, stream>>>(
      desc, WqT, bq, WEMB, ADIM, q, nullptr, ADIM, BATCH / 128, ADIM / 128, 0);
  qnorm_k<<<BATCH, 256, 0, stream>>>(q, qn2);
  // kstats: 256^2 8-phase, grid 1024 (= exactly 4 rounds), N-fast
  gemm256<2><<<128 * 8, 512, 0, stream>>>(
      gpt, WkT, bk, WEMB, ADIM, nullptr, nullptr, nullptr, 0, q, dotb, kn2b,
      BATCH * VIEW / 256, ADIM / 256, 0);
  attn_k<<<BATCH / 256, 256, 0, stream>>>(dotb, kn2b, qn2, asum);
  gtilde_k<<<BATCH, 64, 0, stream>>>(gpt, asum, gt);
  // fused = g~ @ Wv + bv -> concat cols [312, 2360), 128^2
  gemm_bt<1, false><<<16 * 16, 256, 0, stream>>>(
      gt, WvT, bv, WEMB, ADIM, nullptr, cc + ATT, KCATP, BATCH / 128, ADIM / 128, 0);
  // z = relu(concat @ Wm + bm), 128^2 grid 256
  gemm_bt<1, true><<<16 * 16, 256, 0, stream>>>(
      cc, WmT, bm, KCATP, EMB, nullptr, z, EMB, BATCH / 128, EMB / 128, 0);
  // h: split-K=2, grid 256 (exact round): slice0 -> h bf16 (+bias, no relu),
  // slice1 -> Ph fp32; then h = relu(h + Ph) in place.
  gemm256<6><<<256, 512, 0, stream>>>(
      z, Wd1T, bd1, EMB, 4096, nullptr, h, Ph, 4096, nullptr, nullptr, nullptr,
      0, 0, 0);
  relucast2_k<<<(BATCH * 4096) / 2048, 256, 0, stream>>>(h, Ph);
  // out: two-zone. zoneA (blk 0-255): 256 full-K tiles (cols 0..8191) direct.
  // zoneB (blk 256-511): 32 tail tiles split K=8x512; ksl0 direct, 1-7 -> Ptail.
  gemm256<5><<<512, 512, 0, stream>>>(
      h, Wd2T, bd2, 4096, NOUT, out, nullptr, Ptail, NOUT, nullptr, nullptr, nullptr,
      0, 0, 0);
  tailred_k<<<(BATCH * 206 * 4) / 1024, 256, 0, stream>>>(out, Ptail);
}